// Round 1
// baseline (677.324 us; speedup 1.0000x reference)
//
#include <hip/hip_runtime.h>
#include <math.h>

// Problem constants (fixed by the reference setup)
#define NN 50000          // nodes
#define NE 800000         // edges (before self loops)
#define NTE (NE + NN)     // edges incl self loops
#define NG 16             // graphs
#define HID 128           // hidden/out dim (all layers out=128)
#define NEG_SLOPE 0.2f

// ---------------------------------------------------------------------------
// CSR build: deg init (1 = self loop), count, scan (3 kernels), fill
// ---------------------------------------------------------------------------
__global__ void k_deg_init(int* deg) {
    int i = blockIdx.x * blockDim.x + threadIdx.x;
    if (i < NN) deg[i] = 1;   // self loop
}

__global__ void k_deg_count(const int* __restrict__ ei, int* __restrict__ deg) {
    int i = blockIdx.x * blockDim.x + threadIdx.x;
    if (i < NE) atomicAdd(&deg[ei[NE + i]], 1);   // ei[1][i] = dst
}

// per-block inclusive scan -> exclusive partials into off, block totals into bsum
__global__ void k_scan_blocks(const int* __restrict__ deg, int* __restrict__ off,
                              int* __restrict__ bsum) {
    __shared__ int buf[256];
    int t = threadIdx.x;
    int i = blockIdx.x * 256 + t;
    int v = (i < NN) ? deg[i] : 0;
    buf[t] = v;
    __syncthreads();
    #pragma unroll
    for (int o = 1; o < 256; o <<= 1) {
        int add = (t >= o) ? buf[t - o] : 0;
        __syncthreads();
        buf[t] += add;
        __syncthreads();
    }
    if (i < NN) off[i] = buf[t] - v;     // exclusive within block
    if (t == 255) bsum[blockIdx.x] = buf[255];
}

// scan of block sums (NB <= 256); writes exclusive prefixes + total into off[NN]
__global__ void k_scan_top(const int* __restrict__ bsum, int* __restrict__ bpre,
                           int* __restrict__ off_total, int NB) {
    __shared__ int buf[256];
    int t = threadIdx.x;
    int v = (t < NB) ? bsum[t] : 0;
    buf[t] = v;
    __syncthreads();
    #pragma unroll
    for (int o = 1; o < 256; o <<= 1) {
        int add = (t >= o) ? buf[t - o] : 0;
        __syncthreads();
        buf[t] += add;
        __syncthreads();
    }
    if (t < NB) bpre[t] = buf[t] - v;
    if (t == 255) off_total[0] = buf[255];
}

__global__ void k_scan_add(int* __restrict__ off, const int* __restrict__ bpre,
                           int* __restrict__ wr) {
    int i = blockIdx.x * blockDim.x + threadIdx.x;
    if (i < NN) {
        int v = off[i] + bpre[i >> 8];
        off[i] = v;
        wr[i] = v;
    }
}

__global__ void k_fill(const int* __restrict__ ei, int* __restrict__ wr,
                       int* __restrict__ csr) {
    int i = blockIdx.x * blockDim.x + threadIdx.x;
    if (i < NE) {
        int s = ei[i];
        int d = ei[NE + i];
        int pos = atomicAdd(&wr[d], 1);
        csr[pos] = s;
    } else if (i < NTE) {
        int n = i - NE;                // self loop
        int pos = atomicAdd(&wr[n], 1);
        csr[pos] = n;
    }
}

// ---------------------------------------------------------------------------
// FP32 GEMM  C[M x 128] = A[M x K] * B[K x 128]   (K multiple of 32)
// BM=64, BN=128(=full N), BK=32; 256 threads; thread tile 8x4
// ---------------------------------------------------------------------------
__global__ __launch_bounds__(256) void k_gemm(const float* __restrict__ A,
                                              const float* __restrict__ B,
                                              float* __restrict__ C,
                                              int M, int K) {
    __shared__ float As[32][64];    // [k][m]
    __shared__ float Bs[32][128];   // [k][n]
    int tid = threadIdx.x;
    int rowBase = blockIdx.x * 64;
    int ty = tid >> 5;    // 0..7  (row group: rows ty*8 .. ty*8+7)
    int tx = tid & 31;    // 0..31 (col group: cols tx*4 .. tx*4+3)

    float acc[8][4];
    #pragma unroll
    for (int i = 0; i < 8; i++)
        #pragma unroll
        for (int j = 0; j < 4; j++) acc[i][j] = 0.0f;

    int lr = tid & 63;    // loader row 0..63
    int lq = tid >> 6;    // loader quarter 0..3

    for (int k0 = 0; k0 < K; k0 += 32) {
        // --- stage A tile (transposed into [k][m]) ---
        {
            bool rowOK = (rowBase + lr) < M;
            const float* Arow = A + (size_t)(rowBase + lr) * K + k0;
            float4 v0 = {0, 0, 0, 0}, v1 = {0, 0, 0, 0};
            if (rowOK) {
                v0 = *(const float4*)(Arow + 4 * lq);
                v1 = *(const float4*)(Arow + 16 + 4 * lq);
            }
            As[4 * lq + 0][lr] = v0.x;
            As[4 * lq + 1][lr] = v0.y;
            As[4 * lq + 2][lr] = v0.z;
            As[4 * lq + 3][lr] = v0.w;
            As[16 + 4 * lq + 0][lr] = v1.x;
            As[16 + 4 * lq + 1][lr] = v1.y;
            As[16 + 4 * lq + 2][lr] = v1.z;
            As[16 + 4 * lq + 3][lr] = v1.w;
        }
        // --- stage B tile ---
        #pragma unroll
        for (int i = 0; i < 4; i++) {
            int f4 = tid + i * 256;        // 0..1023 float4 index
            int kk = f4 >> 5;              // 32 float4 per k-row
            int nn = (f4 & 31) << 2;
            *(float4*)&Bs[kk][nn] = *(const float4*)(B + (size_t)(k0 + kk) * HID + nn);
        }
        __syncthreads();

        #pragma unroll
        for (int k = 0; k < 32; k++) {
            float4 b4 = *(float4*)&Bs[k][tx * 4];
            float4 a0 = *(float4*)&As[k][ty * 8];
            float4 a1 = *(float4*)&As[k][ty * 8 + 4];
            float a[8] = {a0.x, a0.y, a0.z, a0.w, a1.x, a1.y, a1.z, a1.w};
            float b[4] = {b4.x, b4.y, b4.z, b4.w};
            #pragma unroll
            for (int i = 0; i < 8; i++)
                #pragma unroll
                for (int j = 0; j < 4; j++)
                    acc[i][j] = fmaf(a[i], b[j], acc[i][j]);
        }
        __syncthreads();
    }

    #pragma unroll
    for (int i = 0; i < 8; i++) {
        int row = rowBase + ty * 8 + i;
        if (row < M) {
            float4 v = {acc[i][0], acc[i][1], acc[i][2], acc[i][3]};
            *(float4*)(C + (size_t)row * HID + tx * 4) = v;
        }
    }
}

// ---------------------------------------------------------------------------
// per-node attention logits: als[n] = dot(h[n], a_s), ald[n] = dot(h[n], a_d)
// one wave per node
// ---------------------------------------------------------------------------
__global__ void k_dots(const float* __restrict__ h, const float* __restrict__ a_s,
                       const float* __restrict__ a_d, float* __restrict__ als,
                       float* __restrict__ ald) {
    int gt = blockIdx.x * blockDim.x + threadIdx.x;
    int node = gt >> 6;
    int lane = gt & 63;
    if (node >= NN) return;
    const float* hr = h + (size_t)node * HID;
    float v0 = hr[lane], v1 = hr[lane + 64];
    float s = v0 * a_s[lane] + v1 * a_s[lane + 64];
    float d = v0 * a_d[lane] + v1 * a_d[lane + 64];
    #pragma unroll
    for (int o = 32; o > 0; o >>= 1) {
        s += __shfl_xor(s, o);
        d += __shfl_xor(d, o);
    }
    if (lane == 0) {
        als[node] = s;
        ald[node] = d;
    }
}

// ---------------------------------------------------------------------------
// GAT aggregation: one wave per dst node. Softmax over incoming edges, then
// weighted sum of h[src]. Lane l holds dims {l, l+64}. Atomic-free.
// ---------------------------------------------------------------------------
__global__ void k_agg(const float* __restrict__ h, const float* __restrict__ als,
                      const float* __restrict__ ald, const int* __restrict__ off,
                      const int* __restrict__ csr, const float* __restrict__ bias,
                      float* __restrict__ y, int do_relu) {
    int gt = blockIdx.x * blockDim.x + threadIdx.x;
    int d = gt >> 6;
    int lane = gt & 63;
    if (d >= NN) return;
    int e0 = off[d], e1 = off[d + 1];
    float ald_d = ald[d];

    // phase 1: max logit
    float mx = -INFINITY;
    for (int j = e0 + lane; j < e1; j += 64) {
        float e = als[csr[j]] + ald_d;
        e = (e > 0.0f) ? e : NEG_SLOPE * e;
        mx = fmaxf(mx, e);
    }
    #pragma unroll
    for (int o = 32; o > 0; o >>= 1) mx = fmaxf(mx, __shfl_xor(mx, o));

    // phase 2: denominator
    float z = 0.0f;
    for (int j = e0 + lane; j < e1; j += 64) {
        float e = als[csr[j]] + ald_d;
        e = (e > 0.0f) ? e : NEG_SLOPE * e;
        z += __expf(e - mx);
    }
    #pragma unroll
    for (int o = 32; o > 0; o >>= 1) z += __shfl_xor(z, o);
    float inv_z = 1.0f / z;   // self loop guarantees z > 0

    // phase 3: weighted accumulate (whole wave per edge)
    float acc0 = 0.0f, acc1 = 0.0f;
    for (int j = e0; j < e1; ++j) {
        int s = csr[j];                      // uniform across wave
        float e = als[s] + ald_d;
        e = (e > 0.0f) ? e : NEG_SLOPE * e;
        float coef = __expf(e - mx) * inv_z;
        const float* hr = h + (size_t)s * HID;
        acc0 = fmaf(coef, hr[lane], acc0);
        acc1 = fmaf(coef, hr[lane + 64], acc1);
    }
    float o0 = acc0 + bias[lane];
    float o1 = acc1 + bias[lane + 64];
    if (do_relu) {
        o0 = fmaxf(o0, 0.0f);
        o1 = fmaxf(o1, 0.0f);
    }
    y[(size_t)d * HID + lane] = o0;
    y[(size_t)d * HID + lane + 64] = o1;
}

// ---------------------------------------------------------------------------
// global mean pool: batch is sorted; per-block run-length accumulation
// block = 128 threads (thread t = dim t), processes 128 consecutive nodes
// ---------------------------------------------------------------------------
__global__ void k_pool(const float* __restrict__ emb, const int* __restrict__ batch,
                       float* __restrict__ sums, int* __restrict__ cnt) {
    int t = threadIdx.x;          // dim
    int base = blockIdx.x * 128;
    int end = base + 128;
    if (end > NN) end = NN;
    float acc = 0.0f;
    int g_cur = -1, c = 0;
    for (int n = base; n < end; ++n) {
        int g = batch[n];
        if (g != g_cur) {
            if (g_cur >= 0) {
                atomicAdd(&sums[g_cur * HID + t], acc);
                if (t == 0) atomicAdd(&cnt[g_cur], c);
            }
            acc = 0.0f;
            c = 0;
            g_cur = g;
        }
        acc += emb[(size_t)n * HID + t];
        c++;
    }
    if (g_cur >= 0) {
        atomicAdd(&sums[g_cur * HID + t], acc);
        if (t == 0) atomicAdd(&cnt[g_cur], c);
    }
}

__global__ void k_div(const float* __restrict__ sums, const int* __restrict__ cnt,
                      float* __restrict__ out) {
    int i = blockIdx.x * blockDim.x + threadIdx.x;
    if (i < NG * HID) {
        int g = i >> 7;
        float c = (float)(cnt[g] > 1 ? cnt[g] : 1);
        out[i] = sums[i] / c;
    }
}

// ---------------------------------------------------------------------------
extern "C" void kernel_launch(void* const* d_in, const int* in_sizes, int n_in,
                              void* d_out, int out_size, void* d_ws, size_t ws_size,
                              hipStream_t stream) {
    const float* x     = (const float*)d_in[0];   // [50000,256]
    const int*   ei    = (const int*)d_in[1];     // [2,800000]
    const int*   batch = (const int*)d_in[2];     // [50000]
    const float* W[3]  = {(const float*)d_in[3], (const float*)d_in[7], (const float*)d_in[11]};
    const float* AS[3] = {(const float*)d_in[4], (const float*)d_in[8], (const float*)d_in[12]};
    const float* AD[3] = {(const float*)d_in[5], (const float*)d_in[9], (const float*)d_in[13]};
    const float* BI[3] = {(const float*)d_in[6], (const float*)d_in[10], (const float*)d_in[14]};
    float* out = (float*)d_out;

    // workspace layout (~56 MB)
    char* ws = (char*)d_ws;
    size_t o = 0;
    auto alloc = [&](size_t bytes) {
        void* p = ws + o;
        o = (o + bytes + 255) & ~(size_t)255;
        return p;
    };
    float* hbuf = (float*)alloc((size_t)NN * HID * 4);  // GEMM output
    float* ybuf = (float*)alloc((size_t)NN * HID * 4);  // layer output
    float* als  = (float*)alloc(NN * 4);
    float* ald  = (float*)alloc(NN * 4);
    int* deg    = (int*)alloc(NN * 4);
    int* off    = (int*)alloc((NN + 1) * 4);
    int* wr     = (int*)alloc(NN * 4);
    int* bsum   = (int*)alloc(256 * 4);
    int* bpre   = (int*)alloc(256 * 4);
    int* csr    = (int*)alloc((size_t)NTE * 4);
    float* sums = (float*)alloc(NG * HID * 4);
    int* cnt    = (int*)alloc(NG * 4);
    (void)ws_size; (void)in_sizes; (void)n_in; (void)out_size;

    const int NB = (NN + 255) / 256;   // 196 scan blocks

    // zero pool accumulators (sums + cnt are contiguous in the layout above)
    hipMemsetAsync(sums, 0, NG * HID * 4, stream);
    hipMemsetAsync(cnt, 0, NG * 4, stream);

    // ---- CSR build ----
    k_deg_init<<<NB, 256, 0, stream>>>(deg);
    k_deg_count<<<(NE + 255) / 256, 256, 0, stream>>>(ei, deg);
    k_scan_blocks<<<NB, 256, 0, stream>>>(deg, off, bsum);
    k_scan_top<<<1, 256, 0, stream>>>(bsum, bpre, &off[NN], NB);
    k_scan_add<<<NB, 256, 0, stream>>>(off, bpre, wr);
    k_fill<<<(NTE + 255) / 256, 256, 0, stream>>>(ei, wr, csr);

    const int gemm_grid = (NN + 63) / 64;       // 782
    const int wave_grid = (NN * 64 + 255) / 256; // 12500

    // ---- layer 0 (K=256, relu) ----
    k_gemm<<<gemm_grid, 256, 0, stream>>>(x, W[0], hbuf, NN, 256);
    k_dots<<<wave_grid, 256, 0, stream>>>(hbuf, AS[0], AD[0], als, ald);
    k_agg<<<wave_grid, 256, 0, stream>>>(hbuf, als, ald, off, csr, BI[0], ybuf, 1);

    // ---- layer 1 (K=128, relu) ----
    k_gemm<<<gemm_grid, 256, 0, stream>>>(ybuf, W[1], hbuf, NN, 128);
    k_dots<<<wave_grid, 256, 0, stream>>>(hbuf, AS[1], AD[1], als, ald);
    k_agg<<<wave_grid, 256, 0, stream>>>(hbuf, als, ald, off, csr, BI[1], ybuf, 1);

    // ---- layer 2 (K=128, no relu) ----
    k_gemm<<<gemm_grid, 256, 0, stream>>>(ybuf, W[2], hbuf, NN, 128);
    k_dots<<<wave_grid, 256, 0, stream>>>(hbuf, AS[2], AD[2], als, ald);
    k_agg<<<wave_grid, 256, 0, stream>>>(hbuf, als, ald, off, csr, BI[2], ybuf, 0);

    // ---- global mean pool ----
    k_pool<<<(NN + 127) / 128, 128, 0, stream>>>(ybuf, batch, sums, cnt);
    k_div<<<(NG * HID + 255) / 256, 256, 0, stream>>>(sums, cnt, out);
}

// Round 2
// 565.629 us; speedup vs baseline: 1.1975x; 1.1975x over previous
//
#include <hip/hip_runtime.h>
#include <math.h>

// Problem constants (fixed by the reference setup)
#define NN 50000          // nodes
#define NE 800000         // edges (before self loops)
#define NTE (NE + NN)     // edges incl self loops
#define NG 16             // graphs
#define HID 128           // hidden/out dim (all layers out=128)
#define NEG_SLOPE 0.2f

// ---------------------------------------------------------------------------
// CSR build: deg init (1 = self loop), count, scan (3 kernels), fill
// ---------------------------------------------------------------------------
__global__ void k_deg_init(int* deg) {
    int i = blockIdx.x * blockDim.x + threadIdx.x;
    if (i < NN) deg[i] = 1;   // self loop
}

__global__ void k_deg_count(const int* __restrict__ ei, int* __restrict__ deg) {
    int i = blockIdx.x * blockDim.x + threadIdx.x;
    if (i < NE) atomicAdd(&deg[ei[NE + i]], 1);   // ei[1][i] = dst
}

// per-block inclusive scan -> exclusive partials into off, block totals into bsum
__global__ void k_scan_blocks(const int* __restrict__ deg, int* __restrict__ off,
                              int* __restrict__ bsum) {
    __shared__ int buf[256];
    int t = threadIdx.x;
    int i = blockIdx.x * 256 + t;
    int v = (i < NN) ? deg[i] : 0;
    buf[t] = v;
    __syncthreads();
    #pragma unroll
    for (int o = 1; o < 256; o <<= 1) {
        int add = (t >= o) ? buf[t - o] : 0;
        __syncthreads();
        buf[t] += add;
        __syncthreads();
    }
    if (i < NN) off[i] = buf[t] - v;     // exclusive within block
    if (t == 255) bsum[blockIdx.x] = buf[255];
}

// scan of block sums (NB <= 256); writes exclusive prefixes + total into off[NN]
__global__ void k_scan_top(const int* __restrict__ bsum, int* __restrict__ bpre,
                           int* __restrict__ off_total, int NB) {
    __shared__ int buf[256];
    int t = threadIdx.x;
    int v = (t < NB) ? bsum[t] : 0;
    buf[t] = v;
    __syncthreads();
    #pragma unroll
    for (int o = 1; o < 256; o <<= 1) {
        int add = (t >= o) ? buf[t - o] : 0;
        __syncthreads();
        buf[t] += add;
        __syncthreads();
    }
    if (t < NB) bpre[t] = buf[t] - v;
    if (t == 255) off_total[0] = buf[255];
}

__global__ void k_scan_add(int* __restrict__ off, const int* __restrict__ bpre,
                           int* __restrict__ wr) {
    int i = blockIdx.x * blockDim.x + threadIdx.x;
    if (i < NN) {
        int v = off[i] + bpre[i >> 8];
        off[i] = v;
        wr[i] = v;
    }
}

__global__ void k_fill(const int* __restrict__ ei, int* __restrict__ wr,
                       int* __restrict__ csr) {
    int i = blockIdx.x * blockDim.x + threadIdx.x;
    if (i < NE) {
        int s = ei[i];
        int d = ei[NE + i];
        int pos = atomicAdd(&wr[d], 1);
        csr[pos] = s;
    } else if (i < NTE) {
        int n = i - NE;                // self loop
        int pos = atomicAdd(&wr[n], 1);
        csr[pos] = n;
    }
}

// ---------------------------------------------------------------------------
// FP32 GEMM  C[M x 128] = A[M x K] * B[K x 128]   (K multiple of 32)
// BM=64, BN=128(=full N), BK=32; 256 threads; thread tile 8x4
// Fused epilogue: als[row] = dot(C_row, a_s), ald[row] = dot(C_row, a_d)
// ---------------------------------------------------------------------------
__global__ __launch_bounds__(256) void k_gemm(const float* __restrict__ A,
                                              const float* __restrict__ B,
                                              float* __restrict__ C,
                                              const float* __restrict__ a_s,
                                              const float* __restrict__ a_d,
                                              float* __restrict__ als,
                                              float* __restrict__ ald,
                                              int M, int K) {
    __shared__ float As[32][64];    // [k][m]
    __shared__ float Bs[32][128];   // [k][n]
    int tid = threadIdx.x;
    int rowBase = blockIdx.x * 64;
    int ty = tid >> 5;    // 0..7  (row group: rows ty*8 .. ty*8+7)
    int tx = tid & 31;    // 0..31 (col group: cols tx*4 .. tx*4+3)

    float acc[8][4];
    #pragma unroll
    for (int i = 0; i < 8; i++)
        #pragma unroll
        for (int j = 0; j < 4; j++) acc[i][j] = 0.0f;

    int lr = tid & 63;    // loader row 0..63
    int lq = tid >> 6;    // loader quarter 0..3

    for (int k0 = 0; k0 < K; k0 += 32) {
        // --- stage A tile (transposed into [k][m]) ---
        {
            bool rowOK = (rowBase + lr) < M;
            const float* Arow = A + (size_t)(rowBase + lr) * K + k0;
            float4 v0 = {0, 0, 0, 0}, v1 = {0, 0, 0, 0};
            if (rowOK) {
                v0 = *(const float4*)(Arow + 4 * lq);
                v1 = *(const float4*)(Arow + 16 + 4 * lq);
            }
            As[4 * lq + 0][lr] = v0.x;
            As[4 * lq + 1][lr] = v0.y;
            As[4 * lq + 2][lr] = v0.z;
            As[4 * lq + 3][lr] = v0.w;
            As[16 + 4 * lq + 0][lr] = v1.x;
            As[16 + 4 * lq + 1][lr] = v1.y;
            As[16 + 4 * lq + 2][lr] = v1.z;
            As[16 + 4 * lq + 3][lr] = v1.w;
        }
        // --- stage B tile ---
        #pragma unroll
        for (int i = 0; i < 4; i++) {
            int f4 = tid + i * 256;        // 0..1023 float4 index
            int kk = f4 >> 5;              // 32 float4 per k-row
            int nn = (f4 & 31) << 2;
            *(float4*)&Bs[kk][nn] = *(const float4*)(B + (size_t)(k0 + kk) * HID + nn);
        }
        __syncthreads();

        #pragma unroll
        for (int k = 0; k < 32; k++) {
            float4 b4 = *(float4*)&Bs[k][tx * 4];
            float4 a0 = *(float4*)&As[k][ty * 8];
            float4 a1 = *(float4*)&As[k][ty * 8 + 4];
            float a[8] = {a0.x, a0.y, a0.z, a0.w, a1.x, a1.y, a1.z, a1.w};
            float b[4] = {b4.x, b4.y, b4.z, b4.w};
            #pragma unroll
            for (int i = 0; i < 8; i++)
                #pragma unroll
                for (int j = 0; j < 4; j++)
                    acc[i][j] = fmaf(a[i], b[j], acc[i][j]);
        }
        __syncthreads();
    }

    // store C rows + fused attention dots
    float4 as4 = *(const float4*)(a_s + tx * 4);
    float4 ad4 = *(const float4*)(a_d + tx * 4);
    #pragma unroll
    for (int i = 0; i < 8; i++) {
        int row = rowBase + ty * 8 + i;
        float s = acc[i][0] * as4.x + acc[i][1] * as4.y + acc[i][2] * as4.z + acc[i][3] * as4.w;
        float dd = acc[i][0] * ad4.x + acc[i][1] * ad4.y + acc[i][2] * ad4.z + acc[i][3] * ad4.w;
        // reduce across the 32 tx-lanes (lanes [ty*32, ty*32+31] of the wave)
        #pragma unroll
        for (int o = 16; o > 0; o >>= 1) {
            s += __shfl_xor(s, o);
            dd += __shfl_xor(dd, o);
        }
        if (row < M) {
            float4 v = {acc[i][0], acc[i][1], acc[i][2], acc[i][3]};
            *(float4*)(C + (size_t)row * HID + tx * 4) = v;
            if (tx == 0) {
                als[row] = s;
                ald[row] = dd;
            }
        }
    }
}

// ---------------------------------------------------------------------------
// softmax over incoming edges: one wave per dst node.
// Writes coef[j] = exp(leaky(als[src]+ald[d]) - m) / z for each CSR slot j.
// Common case (deg <= 64) gathers als[csr[j]] exactly once.
// ---------------------------------------------------------------------------
__global__ void k_softmax(const float* __restrict__ als, const float* __restrict__ ald,
                          const int* __restrict__ off, const int* __restrict__ csr,
                          float* __restrict__ coef) {
    int gt = blockIdx.x * blockDim.x + threadIdx.x;
    int d = gt >> 6;
    int lane = gt & 63;
    if (d >= NN) return;
    int e0 = off[d], e1 = off[d + 1];
    float ald_d = ald[d];

    int j0 = e0 + lane;
    float e_first = -INFINITY;
    if (j0 < e1) {
        float e = als[csr[j0]] + ald_d;
        e_first = (e > 0.0f) ? e : NEG_SLOPE * e;
    }
    float mx = e_first;
    for (int j = j0 + 64; j < e1; j += 64) {   // rare: deg > 64
        float e = als[csr[j]] + ald_d;
        e = (e > 0.0f) ? e : NEG_SLOPE * e;
        mx = fmaxf(mx, e);
    }
    #pragma unroll
    for (int o = 32; o > 0; o >>= 1) mx = fmaxf(mx, __shfl_xor(mx, o));

    float p_first = (j0 < e1) ? __expf(e_first - mx) : 0.0f;
    float z = p_first;
    for (int j = j0 + 64; j < e1; j += 64) {
        float e = als[csr[j]] + ald_d;
        e = (e > 0.0f) ? e : NEG_SLOPE * e;
        z += __expf(e - mx);
    }
    #pragma unroll
    for (int o = 32; o > 0; o >>= 1) z += __shfl_xor(z, o);
    float inv_z = 1.0f / z;   // self loop guarantees z > 0

    if (j0 < e1) coef[j0] = p_first * inv_z;
    for (int j = j0 + 64; j < e1; j += 64) {
        float e = als[csr[j]] + ald_d;
        e = (e > 0.0f) ? e : NEG_SLOPE * e;
        coef[j] = __expf(e - mx) * inv_z;
    }
}

// ---------------------------------------------------------------------------
// weighted gather: one wave per dst node, two edges in flight (half-wave each),
// float4 per lane. y[d] = sum_j coef[j] * h[csr[j]] + bias (+relu)
// ---------------------------------------------------------------------------
__global__ void k_gather(const float* __restrict__ h, const int* __restrict__ off,
                         const int* __restrict__ csr, const float* __restrict__ coef,
                         const float* __restrict__ bias, float* __restrict__ y,
                         int do_relu) {
    int gt = blockIdx.x * blockDim.x + threadIdx.x;
    int d = gt >> 6;
    int lane = gt & 63;
    if (d >= NN) return;
    int sub = lane >> 5;      // 0 or 1: which edge of the pair
    int q = lane & 31;        // float4 index within the 128-dim row

    int e0 = off[d], e1 = off[d + 1];
    float4 acc = {0.0f, 0.0f, 0.0f, 0.0f};
    #pragma unroll 2
    for (int j = e0 + sub; j < e1; j += 2) {
        int s = csr[j];                       // uniform within half-wave
        float c = coef[j];
        float4 v = ((const float4*)(h + (size_t)s * HID))[q];
        acc.x = fmaf(c, v.x, acc.x);
        acc.y = fmaf(c, v.y, acc.y);
        acc.z = fmaf(c, v.z, acc.z);
        acc.w = fmaf(c, v.w, acc.w);
    }
    // combine the two half-waves
    acc.x += __shfl_xor(acc.x, 32);
    acc.y += __shfl_xor(acc.y, 32);
    acc.z += __shfl_xor(acc.z, 32);
    acc.w += __shfl_xor(acc.w, 32);

    if (sub == 0) {
        float4 b4 = *(const float4*)(bias + q * 4);
        acc.x += b4.x; acc.y += b4.y; acc.z += b4.z; acc.w += b4.w;
        if (do_relu) {
            acc.x = fmaxf(acc.x, 0.0f);
            acc.y = fmaxf(acc.y, 0.0f);
            acc.z = fmaxf(acc.z, 0.0f);
            acc.w = fmaxf(acc.w, 0.0f);
        }
        ((float4*)(y + (size_t)d * HID))[q] = acc;
    }
}

// ---------------------------------------------------------------------------
// global mean pool: batch is sorted; per-block run-length accumulation
// ---------------------------------------------------------------------------
__global__ void k_pool(const float* __restrict__ emb, const int* __restrict__ batch,
                       float* __restrict__ sums, int* __restrict__ cnt) {
    int t = threadIdx.x;          // dim
    int base = blockIdx.x * 128;
    int end = base + 128;
    if (end > NN) end = NN;
    float acc = 0.0f;
    int g_cur = -1, c = 0;
    for (int n = base; n < end; ++n) {
        int g = batch[n];
        if (g != g_cur) {
            if (g_cur >= 0) {
                atomicAdd(&sums[g_cur * HID + t], acc);
                if (t == 0) atomicAdd(&cnt[g_cur], c);
            }
            acc = 0.0f;
            c = 0;
            g_cur = g;
        }
        acc += emb[(size_t)n * HID + t];
        c++;
    }
    if (g_cur >= 0) {
        atomicAdd(&sums[g_cur * HID + t], acc);
        if (t == 0) atomicAdd(&cnt[g_cur], c);
    }
}

__global__ void k_div(const float* __restrict__ sums, const int* __restrict__ cnt,
                      float* __restrict__ out) {
    int i = blockIdx.x * blockDim.x + threadIdx.x;
    if (i < NG * HID) {
        int g = i >> 7;
        float c = (float)(cnt[g] > 1 ? cnt[g] : 1);
        out[i] = sums[i] / c;
    }
}

// ---------------------------------------------------------------------------
extern "C" void kernel_launch(void* const* d_in, const int* in_sizes, int n_in,
                              void* d_out, int out_size, void* d_ws, size_t ws_size,
                              hipStream_t stream) {
    const float* x     = (const float*)d_in[0];   // [50000,256]
    const int*   ei    = (const int*)d_in[1];     // [2,800000]
    const int*   batch = (const int*)d_in[2];     // [50000]
    const float* W[3]  = {(const float*)d_in[3], (const float*)d_in[7], (const float*)d_in[11]};
    const float* AS[3] = {(const float*)d_in[4], (const float*)d_in[8], (const float*)d_in[12]};
    const float* AD[3] = {(const float*)d_in[5], (const float*)d_in[9], (const float*)d_in[13]};
    const float* BI[3] = {(const float*)d_in[6], (const float*)d_in[10], (const float*)d_in[14]};
    float* out = (float*)d_out;

    // workspace layout (~62 MB)
    char* ws = (char*)d_ws;
    size_t o = 0;
    auto alloc = [&](size_t bytes) {
        void* p = ws + o;
        o = (o + bytes + 255) & ~(size_t)255;
        return p;
    };
    float* hbuf = (float*)alloc((size_t)NN * HID * 4);  // GEMM output
    float* ybuf = (float*)alloc((size_t)NN * HID * 4);  // layer output
    float* als  = (float*)alloc(NN * 4);
    float* ald  = (float*)alloc(NN * 4);
    int* deg    = (int*)alloc(NN * 4);
    int* off    = (int*)alloc((NN + 1) * 4);
    int* wr     = (int*)alloc(NN * 4);
    int* bsum   = (int*)alloc(256 * 4);
    int* bpre   = (int*)alloc(256 * 4);
    int* csr    = (int*)alloc((size_t)NTE * 4);
    float* coef = (float*)alloc((size_t)NTE * 4);
    float* sums = (float*)alloc(NG * HID * 4);
    int* cnt    = (int*)alloc(NG * 4);
    (void)ws_size; (void)in_sizes; (void)n_in; (void)out_size;

    const int NB = (NN + 255) / 256;   // 196 scan blocks

    hipMemsetAsync(sums, 0, NG * HID * 4, stream);
    hipMemsetAsync(cnt, 0, NG * 4, stream);

    // ---- CSR build ----
    k_deg_init<<<NB, 256, 0, stream>>>(deg);
    k_deg_count<<<(NE + 255) / 256, 256, 0, stream>>>(ei, deg);
    k_scan_blocks<<<NB, 256, 0, stream>>>(deg, off, bsum);
    k_scan_top<<<1, 256, 0, stream>>>(bsum, bpre, &off[NN], NB);
    k_scan_add<<<NB, 256, 0, stream>>>(off, bpre, wr);
    k_fill<<<(NTE + 255) / 256, 256, 0, stream>>>(ei, wr, csr);

    const int gemm_grid = (NN + 63) / 64;        // 782
    const int wave_grid = (NN * 64 + 255) / 256; // 12500

    // ---- layer 0 (K=256, relu) ----
    k_gemm<<<gemm_grid, 256, 0, stream>>>(x, W[0], hbuf, AS[0], AD[0], als, ald, NN, 256);
    k_softmax<<<wave_grid, 256, 0, stream>>>(als, ald, off, csr, coef);
    k_gather<<<wave_grid, 256, 0, stream>>>(hbuf, off, csr, coef, BI[0], ybuf, 1);

    // ---- layer 1 (K=128, relu) ----
    k_gemm<<<gemm_grid, 256, 0, stream>>>(ybuf, W[1], hbuf, AS[1], AD[1], als, ald, NN, 128);
    k_softmax<<<wave_grid, 256, 0, stream>>>(als, ald, off, csr, coef);
    k_gather<<<wave_grid, 256, 0, stream>>>(hbuf, off, csr, coef, BI[1], ybuf, 1);

    // ---- layer 2 (K=128, no relu) ----
    k_gemm<<<gemm_grid, 256, 0, stream>>>(ybuf, W[2], hbuf, AS[2], AD[2], als, ald, NN, 128);
    k_softmax<<<wave_grid, 256, 0, stream>>>(als, ald, off, csr, coef);
    k_gather<<<wave_grid, 256, 0, stream>>>(hbuf, off, csr, coef, BI[2], ybuf, 0);

    // ---- global mean pool ----
    k_pool<<<(NN + 127) / 128, 128, 0, stream>>>(ybuf, batch, sums, cnt);
    k_div<<<(NG * HID + 255) / 256, 256, 0, stream>>>(sums, cnt, out);
}

// Round 3
// 444.521 us; speedup vs baseline: 1.5237x; 1.2724x over previous
//
#include <hip/hip_runtime.h>
#include <math.h>

// Problem constants (fixed by the reference setup)
#define NN 50000          // nodes
#define NE 800000         // edges (before self loops)
#define NTE (NE + NN)     // edges incl self loops
#define NG 16             // graphs
#define HID 128           // hidden/out dim (all layers out=128)
#define NEG_SLOPE 0.2f

typedef __attribute__((ext_vector_type(8))) __bf16 bf16x8;
typedef __attribute__((ext_vector_type(4))) float f32x4;

union V16 {
    float4 f4;
    bf16x8 b8;
    __bf16 h[8];
};

// ---------------------------------------------------------------------------
// CSR build: deg init (1 = self loop), count, scan (3 kernels), fill
// ---------------------------------------------------------------------------
__global__ void k_deg_init(int* deg) {
    int i = blockIdx.x * blockDim.x + threadIdx.x;
    if (i < NN) deg[i] = 1;   // self loop
}

__global__ void k_deg_count(const int* __restrict__ ei, int* __restrict__ deg) {
    int i = blockIdx.x * blockDim.x + threadIdx.x;
    if (i < NE) atomicAdd(&deg[ei[NE + i]], 1);   // ei[1][i] = dst
}

__global__ void k_scan_blocks(const int* __restrict__ deg, int* __restrict__ off,
                              int* __restrict__ bsum) {
    __shared__ int buf[256];
    int t = threadIdx.x;
    int i = blockIdx.x * 256 + t;
    int v = (i < NN) ? deg[i] : 0;
    buf[t] = v;
    __syncthreads();
    #pragma unroll
    for (int o = 1; o < 256; o <<= 1) {
        int add = (t >= o) ? buf[t - o] : 0;
        __syncthreads();
        buf[t] += add;
        __syncthreads();
    }
    if (i < NN) off[i] = buf[t] - v;     // exclusive within block
    if (t == 255) bsum[blockIdx.x] = buf[255];
}

__global__ void k_scan_top(const int* __restrict__ bsum, int* __restrict__ bpre,
                           int* __restrict__ off_total, int NB) {
    __shared__ int buf[256];
    int t = threadIdx.x;
    int v = (t < NB) ? bsum[t] : 0;
    buf[t] = v;
    __syncthreads();
    #pragma unroll
    for (int o = 1; o < 256; o <<= 1) {
        int add = (t >= o) ? buf[t - o] : 0;
        __syncthreads();
        buf[t] += add;
        __syncthreads();
    }
    if (t < NB) bpre[t] = buf[t] - v;
    if (t == 255) off_total[0] = buf[255];
}

__global__ void k_scan_add(int* __restrict__ off, const int* __restrict__ bpre,
                           int* __restrict__ wr) {
    int i = blockIdx.x * blockDim.x + threadIdx.x;
    if (i < NN) {
        int v = off[i] + bpre[i >> 8];
        off[i] = v;
        wr[i] = v;
    }
}

__global__ void k_fill(const int* __restrict__ ei, int* __restrict__ wr,
                       int* __restrict__ csr) {
    int i = blockIdx.x * blockDim.x + threadIdx.x;
    if (i < NE) {
        int s = ei[i];
        int d = ei[NE + i];
        int pos = atomicAdd(&wr[d], 1);
        csr[pos] = s;
    } else if (i < NTE) {
        int n = i - NE;                // self loop
        int pos = atomicAdd(&wr[n], 1);
        csr[pos] = n;
    }
}

// ---------------------------------------------------------------------------
// conversions
// ---------------------------------------------------------------------------
__global__ void k_cvt_x(const float* __restrict__ in, __bf16* __restrict__ out, int n8) {
    int i = blockIdx.x * blockDim.x + threadIdx.x;   // chunk of 8
    if (i >= n8) return;
    const float* p = in + (size_t)i * 8;
    V16 o;
    #pragma unroll
    for (int t = 0; t < 8; t++) o.h[t] = (__bf16)p[t];
    *(float4*)(out + (size_t)i * 8) = o.f4;
}

// W [K][128] fp32 -> Wt [128][K] bf16
__global__ void k_cvt_wt(const float* __restrict__ W, __bf16* __restrict__ Wt, int K) {
    int t = blockIdx.x * blockDim.x + threadIdx.x;
    if (t >= K * HID) return;
    int k = t >> 7;
    int n = t & 127;
    Wt[(size_t)n * K + k] = (__bf16)W[t];
}

// ---------------------------------------------------------------------------
// MFMA GEMM  C[M x 128] = A[M x K] * B[K x 128],  A bf16 row-major,
// Bt = B^T bf16 [128 x K].  C bf16 out.  BM=128, BN=128, BK=32.
// 256 threads = 4 waves; wave w covers rows [w*32, w*32+32), all 128 cols
// => 2x8 grid of 16x16x32 MFMA tiles, fp32 accum.
// Fused epilogue: als[row]=dot(Crow,a_s), ald[row]=dot(Crow,a_d)  (fp32 acc)
// ---------------------------------------------------------------------------
__global__ __launch_bounds__(256) void k_gemm(const __bf16* __restrict__ A,
                                              const __bf16* __restrict__ Bt,
                                              __bf16* __restrict__ C,
                                              const float* __restrict__ a_s,
                                              const float* __restrict__ a_d,
                                              float* __restrict__ als,
                                              float* __restrict__ ald,
                                              int M, int K) {
    __shared__ __align__(16) __bf16 As[128][40];   // padded: 80 B rows
    __shared__ __align__(16) __bf16 Bs[128][40];

    int tid = threadIdx.x;
    int rowBase = blockIdx.x * 128;
    int wv = tid >> 6;        // wave 0..3
    int lane = tid & 63;
    int g = lane >> 4;        // k-slice selector (0..3)
    int c = lane & 15;        // col-in-tile / row-in-tile selector

    f32x4 acc[2][8];
    #pragma unroll
    for (int mi = 0; mi < 2; mi++)
        #pragma unroll
        for (int ni = 0; ni < 8; ni++) acc[mi][ni] = (f32x4){0.f, 0.f, 0.f, 0.f};

    for (int k0 = 0; k0 < K; k0 += 32) {
        __syncthreads();
        // stage A tile: 128 rows x 32 k  (512 chunks of 8 bf16)
        #pragma unroll
        for (int rep = 0; rep < 2; rep++) {
            int ch = tid + rep * 256;
            int r = ch >> 2, q = ch & 3;
            int row = rowBase + r;
            float4 v = {0.f, 0.f, 0.f, 0.f};
            if (row < M) v = *(const float4*)(A + (size_t)row * K + k0 + q * 8);
            *(float4*)&As[r][q * 8] = v;
        }
        // stage Bt tile: 128 rows x 32 k
        #pragma unroll
        for (int rep = 0; rep < 2; rep++) {
            int ch = tid + rep * 256;
            int r = ch >> 2, q = ch & 3;
            float4 v = *(const float4*)(Bt + (size_t)r * K + k0 + q * 8);
            *(float4*)&Bs[r][q * 8] = v;
        }
        __syncthreads();

        bf16x8 a0 = *(const bf16x8*)&As[wv * 32 + c][g * 8];
        bf16x8 a1 = *(const bf16x8*)&As[wv * 32 + 16 + c][g * 8];
        #pragma unroll
        for (int ni = 0; ni < 8; ni++) {
            bf16x8 b = *(const bf16x8*)&Bs[ni * 16 + c][g * 8];
            acc[0][ni] = __builtin_amdgcn_mfma_f32_16x16x32_bf16(a0, b, acc[0][ni], 0, 0, 0);
            acc[1][ni] = __builtin_amdgcn_mfma_f32_16x16x32_bf16(a1, b, acc[1][ni], 0, 0, 0);
        }
    }

    // epilogue: C store (bf16) + fused attention dots
    float asv[8], adv[8];
    #pragma unroll
    for (int ni = 0; ni < 8; ni++) {
        asv[ni] = a_s[ni * 16 + c];
        adv[ni] = a_d[ni * 16 + c];
    }
    #pragma unroll
    for (int mi = 0; mi < 2; mi++) {
        int rb = rowBase + wv * 32 + mi * 16 + g * 4;
        #pragma unroll
        for (int i = 0; i < 4; i++) {
            int row = rb + i;
            float s = 0.f, dd = 0.f;
            #pragma unroll
            for (int ni = 0; ni < 8; ni++) {
                float v = acc[mi][ni][i];
                s = fmaf(v, asv[ni], s);
                dd = fmaf(v, adv[ni], dd);
            }
            #pragma unroll
            for (int o = 1; o <= 8; o <<= 1) {
                s += __shfl_xor(s, o);
                dd += __shfl_xor(dd, o);
            }
            if (row < M) {
                #pragma unroll
                for (int ni = 0; ni < 8; ni++)
                    C[(size_t)row * HID + ni * 16 + c] = (__bf16)acc[mi][ni][i];
                if (c == 0) {
                    als[row] = s;
                    ald[row] = dd;
                }
            }
        }
    }
}

// ---------------------------------------------------------------------------
// softmax over incoming edges: one wave per dst node.
// coef[j] = exp(leaky(als[src]+ald[d]) - m) / z in CSR order.
// ---------------------------------------------------------------------------
__global__ void k_softmax(const float* __restrict__ als, const float* __restrict__ ald,
                          const int* __restrict__ off, const int* __restrict__ csr,
                          float* __restrict__ coef) {
    int gt = blockIdx.x * blockDim.x + threadIdx.x;
    int d = gt >> 6;
    int lane = gt & 63;
    if (d >= NN) return;
    int e0 = off[d], e1 = off[d + 1];
    float ald_d = ald[d];

    int j0 = e0 + lane;
    float e_first = -INFINITY;
    if (j0 < e1) {
        float e = als[csr[j0]] + ald_d;
        e_first = (e > 0.0f) ? e : NEG_SLOPE * e;
    }
    float mx = e_first;
    for (int j = j0 + 64; j < e1; j += 64) {   // rare: deg > 64
        float e = als[csr[j]] + ald_d;
        e = (e > 0.0f) ? e : NEG_SLOPE * e;
        mx = fmaxf(mx, e);
    }
    #pragma unroll
    for (int o = 32; o > 0; o >>= 1) mx = fmaxf(mx, __shfl_xor(mx, o));

    float p_first = (j0 < e1) ? __expf(e_first - mx) : 0.0f;
    float z = p_first;
    for (int j = j0 + 64; j < e1; j += 64) {
        float e = als[csr[j]] + ald_d;
        e = (e > 0.0f) ? e : NEG_SLOPE * e;
        z += __expf(e - mx);
    }
    #pragma unroll
    for (int o = 32; o > 0; o >>= 1) z += __shfl_xor(z, o);
    float inv_z = 1.0f / z;   // self loop guarantees z > 0

    if (j0 < e1) coef[j0] = p_first * inv_z;
    for (int j = j0 + 64; j < e1; j += 64) {
        float e = als[csr[j]] + ald_d;
        e = (e > 0.0f) ? e : NEG_SLOPE * e;
        coef[j] = __expf(e - mx) * inv_z;
    }
}

// ---------------------------------------------------------------------------
// weighted gather: one wave per dst node, 4 edges in flight (16 lanes each),
// lane's 16-lane group covers one edge; each lane loads 8 bf16 (16 B).
// y = sum_j coef[j] * h[csr[j]] + bias (+relu). out bf16 or fp32.
// ---------------------------------------------------------------------------
__global__ void k_gather(const __bf16* __restrict__ h, const int* __restrict__ off,
                         const int* __restrict__ csr, const float* __restrict__ coef,
                         const float* __restrict__ bias, void* __restrict__ yout,
                         int do_relu, int out_bf16) {
    int gt = blockIdx.x * blockDim.x + threadIdx.x;
    int d = gt >> 6;
    int lane = gt & 63;
    if (d >= NN) return;
    int grp = lane >> 4;      // edge slot 0..3
    int c = lane & 15;        // dim block (8 dims: c*8 .. c*8+7)

    int e0 = off[d], e1 = off[d + 1];
    float acc[8] = {0.f, 0.f, 0.f, 0.f, 0.f, 0.f, 0.f, 0.f};
    #pragma unroll 2
    for (int j = e0 + grp; j < e1; j += 4) {
        int s = csr[j];                  // uniform within 16-lane group
        float cf = coef[j];
        V16 v;
        v.f4 = *(const float4*)(h + (size_t)s * HID + c * 8);
        #pragma unroll
        for (int t = 0; t < 8; t++) acc[t] = fmaf(cf, (float)v.h[t], acc[t]);
    }
    // combine the 4 groups
    #pragma unroll
    for (int t = 0; t < 8; t++) {
        acc[t] += __shfl_xor(acc[t], 16);
        acc[t] += __shfl_xor(acc[t], 32);
    }

    if (grp == 0) {
        float4 b0 = *(const float4*)(bias + c * 8);
        float4 b1 = *(const float4*)(bias + c * 8 + 4);
        acc[0] += b0.x; acc[1] += b0.y; acc[2] += b0.z; acc[3] += b0.w;
        acc[4] += b1.x; acc[5] += b1.y; acc[6] += b1.z; acc[7] += b1.w;
        if (do_relu) {
            #pragma unroll
            for (int t = 0; t < 8; t++) acc[t] = fmaxf(acc[t], 0.0f);
        }
        if (out_bf16) {
            V16 o;
            #pragma unroll
            for (int t = 0; t < 8; t++) o.h[t] = (__bf16)acc[t];
            *(float4*)((__bf16*)yout + (size_t)d * HID + c * 8) = o.f4;
        } else {
            float* yf = (float*)yout + (size_t)d * HID + c * 8;
            float4 o0 = {acc[0], acc[1], acc[2], acc[3]};
            float4 o1 = {acc[4], acc[5], acc[6], acc[7]};
            *(float4*)yf = o0;
            *(float4*)(yf + 4) = o1;
        }
    }
}

// ---------------------------------------------------------------------------
// global mean pool: batch is sorted; per-block run-length accumulation
// ---------------------------------------------------------------------------
__global__ void k_pool(const float* __restrict__ emb, const int* __restrict__ batch,
                       float* __restrict__ sums, int* __restrict__ cnt) {
    int t = threadIdx.x;          // dim
    int base = blockIdx.x * 128;
    int end = base + 128;
    if (end > NN) end = NN;
    float acc = 0.0f;
    int g_cur = -1, c = 0;
    for (int n = base; n < end; ++n) {
        int g = batch[n];
        if (g != g_cur) {
            if (g_cur >= 0) {
                atomicAdd(&sums[g_cur * HID + t], acc);
                if (t == 0) atomicAdd(&cnt[g_cur], c);
            }
            acc = 0.0f;
            c = 0;
            g_cur = g;
        }
        acc += emb[(size_t)n * HID + t];
        c++;
    }
    if (g_cur >= 0) {
        atomicAdd(&sums[g_cur * HID + t], acc);
        if (t == 0) atomicAdd(&cnt[g_cur], c);
    }
}

__global__ void k_div(const float* __restrict__ sums, const int* __restrict__ cnt,
                      float* __restrict__ out) {
    int i = blockIdx.x * blockDim.x + threadIdx.x;
    if (i < NG * HID) {
        int g = i >> 7;
        float c = (float)(cnt[g] > 1 ? cnt[g] : 1);
        out[i] = sums[i] / c;
    }
}

// ---------------------------------------------------------------------------
extern "C" void kernel_launch(void* const* d_in, const int* in_sizes, int n_in,
                              void* d_out, int out_size, void* d_ws, size_t ws_size,
                              hipStream_t stream) {
    const float* x     = (const float*)d_in[0];   // [50000,256]
    const int*   ei    = (const int*)d_in[1];     // [2,800000]
    const int*   batch = (const int*)d_in[2];     // [50000]
    const float* W[3]  = {(const float*)d_in[3], (const float*)d_in[7], (const float*)d_in[11]};
    const float* AS[3] = {(const float*)d_in[4], (const float*)d_in[8], (const float*)d_in[12]};
    const float* AD[3] = {(const float*)d_in[5], (const float*)d_in[9], (const float*)d_in[13]};
    const float* BI[3] = {(const float*)d_in[6], (const float*)d_in[10], (const float*)d_in[14]};
    float* out = (float*)d_out;

    // workspace layout (~60 MB)
    char* ws = (char*)d_ws;
    size_t o = 0;
    auto alloc = [&](size_t bytes) {
        void* p = ws + o;
        o = (o + bytes + 255) & ~(size_t)255;
        return p;
    };
    __bf16* xb  = (__bf16*)alloc((size_t)NN * 256 * 2);   // x in bf16 (25.6 MB)
    __bf16* hb  = (__bf16*)alloc((size_t)NN * HID * 2);   // GEMM output (12.8 MB)
    __bf16* yb  = (__bf16*)alloc((size_t)NN * HID * 2);   // layer output bf16 (12.8 MB)
    __bf16* Wt0 = (__bf16*)alloc((size_t)256 * HID * 2);
    __bf16* Wt1 = (__bf16*)alloc((size_t)HID * HID * 2);
    __bf16* Wt2 = (__bf16*)alloc((size_t)HID * HID * 2);
    float* als  = (float*)alloc(NN * 4);
    float* ald  = (float*)alloc(NN * 4);
    int* deg    = (int*)alloc(NN * 4);
    int* off    = (int*)alloc((NN + 1) * 4);
    int* wr     = (int*)alloc(NN * 4);
    int* bsum   = (int*)alloc(256 * 4);
    int* bpre   = (int*)alloc(256 * 4);
    int* csr    = (int*)alloc((size_t)NTE * 4);
    float* coef = (float*)alloc((size_t)NTE * 4);
    float* sums = (float*)alloc(NG * HID * 4);
    int* cnt    = (int*)alloc(NG * 4);
    // final fp32 layer output aliases xb (xb dead after GEMM0)
    float* yout = (float*)xb;
    (void)ws_size; (void)in_sizes; (void)n_in; (void)out_size;

    const int NB = (NN + 255) / 256;   // 196 scan blocks

    hipMemsetAsync(sums, 0, NG * HID * 4, stream);
    hipMemsetAsync(cnt, 0, NG * 4, stream);

    // ---- conversions ----
    k_cvt_x<<<(NN * 256 / 8 + 255) / 256, 256, 0, stream>>>(x, xb, NN * 256 / 8);
    k_cvt_wt<<<(256 * HID + 255) / 256, 256, 0, stream>>>(W[0], Wt0, 256);
    k_cvt_wt<<<(HID * HID + 255) / 256, 256, 0, stream>>>(W[1], Wt1, HID);
    k_cvt_wt<<<(HID * HID + 255) / 256, 256, 0, stream>>>(W[2], Wt2, HID);

    // ---- CSR build ----
    k_deg_init<<<NB, 256, 0, stream>>>(deg);
    k_deg_count<<<(NE + 255) / 256, 256, 0, stream>>>(ei, deg);
    k_scan_blocks<<<NB, 256, 0, stream>>>(deg, off, bsum);
    k_scan_top<<<1, 256, 0, stream>>>(bsum, bpre, &off[NN], NB);
    k_scan_add<<<NB, 256, 0, stream>>>(off, bpre, wr);
    k_fill<<<(NTE + 255) / 256, 256, 0, stream>>>(ei, wr, csr);

    const int gemm_grid = (NN + 127) / 128;      // 391
    const int wave_grid = (NN * 64 + 255) / 256; // 12500

    // ---- layer 0 (K=256, relu) ----
    k_gemm<<<gemm_grid, 256, 0, stream>>>(xb, Wt0, hb, AS[0], AD[0], als, ald, NN, 256);
    k_softmax<<<wave_grid, 256, 0, stream>>>(als, ald, off, csr, coef);
    k_gather<<<wave_grid, 256, 0, stream>>>(hb, off, csr, coef, BI[0], yb, 1, 1);

    // ---- layer 1 (K=128, relu) ----
    k_gemm<<<gemm_grid, 256, 0, stream>>>(yb, Wt1, hb, AS[1], AD[1], als, ald, NN, HID);
    k_softmax<<<wave_grid, 256, 0, stream>>>(als, ald, off, csr, coef);
    k_gather<<<wave_grid, 256, 0, stream>>>(hb, off, csr, coef, BI[1], yb, 1, 1);

    // ---- layer 2 (K=128, no relu) ----
    k_gemm<<<gemm_grid, 256, 0, stream>>>(yb, Wt2, hb, AS[2], AD[2], als, ald, NN, HID);
    k_softmax<<<wave_grid, 256, 0, stream>>>(als, ald, off, csr, coef);
    k_gather<<<wave_grid, 256, 0, stream>>>(hb, off, csr, coef, BI[2], yout, 0, 0);

    // ---- global mean pool ----
    k_pool<<<(NN + 127) / 128, 128, 0, stream>>>(yout, batch, sums, cnt);
    k_div<<<(NG * HID + 255) / 256, 256, 0, stream>>>(sums, cnt, out);
}

// Round 5
// 385.671 us; speedup vs baseline: 1.7562x; 1.1526x over previous
//
#include <hip/hip_runtime.h>
#include <math.h>

// Problem constants (fixed by the reference setup)
#define NN 50000          // nodes
#define NE 800000         // edges (before self loops)
#define NTE (NE + NN)     // edges incl self loops
#define NG 16             // graphs
#define HID 128           // hidden/out dim (all layers out=128)
#define NEG_SLOPE 0.2f

#define NBUK 391          // ceil(NN/128) buckets of 128 dst nodes
#define EPW 4096          // edges per workgroup in bucket count/scatter
#define NWG_E ((NTE + EPW - 1) / EPW)   // 208

typedef __attribute__((ext_vector_type(8))) __bf16 bf16x8;
typedef __attribute__((ext_vector_type(4))) float f32x4;

union V16 {
    float4 f4;
    bf16x8 b8;
    __bf16 h[8];
};

// ---------------------------------------------------------------------------
// Bucketed CSR build.  rec[] holds src | (dst&127)<<17, grouped by bucket.
// ---------------------------------------------------------------------------
__global__ __launch_bounds__(256) void k_bcnt(const int* __restrict__ ei,
                                              int* __restrict__ bcnt) {
    __shared__ int hist[NBUK];
    int tid = threadIdx.x;
    for (int b = tid; b < NBUK; b += 256) hist[b] = 0;
    __syncthreads();
    int base = blockIdx.x * EPW;
    #pragma unroll
    for (int r = 0; r < EPW / 256; r++) {
        int idx = base + r * 256 + tid;
        if (idx < NTE) {
            int dst = (idx < NE) ? ei[NE + idx] : (idx - NE);
            atomicAdd(&hist[dst >> 7], 1);
        }
    }
    __syncthreads();
    for (int b = tid; b < NBUK; b += 256) {
        int c = hist[b];
        if (c) atomicAdd(&bcnt[b], c);
    }
}

__global__ void k_bscan(const int* __restrict__ bcnt, int* __restrict__ bbase,
                        int* __restrict__ off) {
    __shared__ int buf[512];
    int t = threadIdx.x;
    int v = (t < NBUK) ? bcnt[t] : 0;
    buf[t] = v;
    __syncthreads();
    #pragma unroll
    for (int o = 1; o < 512; o <<= 1) {
        int add = (t >= o) ? buf[t - o] : 0;
        __syncthreads();
        buf[t] += add;
        __syncthreads();
    }
    if (t < NBUK) bbase[t] = buf[t] - v;   // exclusive
    if (t == 0) {
        bbase[NBUK] = NTE;
        off[NN] = NTE;
    }
}

__global__ __launch_bounds__(256) void k_scatter(const int* __restrict__ ei,
                                                 const int* __restrict__ bbase,
                                                 int* __restrict__ bwr,
                                                 int* __restrict__ rec) {
    __shared__ int hist[NBUK];
    __shared__ int cur[NBUK];
    int tid = threadIdx.x;
    for (int b = tid; b < NBUK; b += 256) hist[b] = 0;
    __syncthreads();
    int base = blockIdx.x * EPW;
    #pragma unroll
    for (int r = 0; r < EPW / 256; r++) {
        int idx = base + r * 256 + tid;
        if (idx < NTE) {
            int dst = (idx < NE) ? ei[NE + idx] : (idx - NE);
            atomicAdd(&hist[dst >> 7], 1);
        }
    }
    __syncthreads();
    for (int b = tid; b < NBUK; b += 256) {
        int c = hist[b];
        if (c) cur[b] = bbase[b] + atomicAdd(&bwr[b], c);
    }
    __syncthreads();
    #pragma unroll
    for (int r = 0; r < EPW / 256; r++) {
        int idx = base + r * 256 + tid;
        if (idx < NTE) {
            int src, dst;
            if (idx < NE) { src = ei[idx]; dst = ei[NE + idx]; }
            else          { src = idx - NE; dst = src; }
            int pos = atomicAdd(&cur[dst >> 7], 1);
            rec[pos] = src | ((dst & 127) << 17);
        }
    }
}

// one workgroup per bucket: local 128-scan -> off[], place src into csr window
__global__ __launch_bounds__(256) void k_bfill(const int* __restrict__ bbase,
                                               const int* __restrict__ rec,
                                               int* __restrict__ off,
                                               int* __restrict__ csr) {
    __shared__ int cnt[128];
    __shared__ int scn[128];
    __shared__ int cur[128];
    int b = blockIdx.x, t = threadIdx.x;
    int base = bbase[b];
    int n = bbase[b + 1] - base;
    if (t < 128) cnt[t] = 0;
    __syncthreads();
    for (int i = t; i < n; i += 256) atomicAdd(&cnt[rec[base + i] >> 17], 1);
    __syncthreads();
    if (t < 128) scn[t] = cnt[t];
    __syncthreads();
    #pragma unroll
    for (int o = 1; o < 128; o <<= 1) {
        int add = (t >= o && t < 128) ? scn[t - o] : 0;
        __syncthreads();
        if (t < 128) scn[t] += add;
        __syncthreads();
    }
    if (t < 128) {
        int ex = scn[t] - cnt[t];
        cur[t] = ex;
        int d = b * 128 + t;
        if (d < NN) off[d] = base + ex;
    }
    __syncthreads();
    for (int i = t; i < n; i += 256) {
        int r = rec[base + i];
        int dloc = r >> 17;
        int src = r & 131071;
        int pos = atomicAdd(&cur[dloc], 1);
        csr[base + pos] = src;
    }
}

// ---------------------------------------------------------------------------
// conversions
// ---------------------------------------------------------------------------
__global__ void k_cvt_x(const float* __restrict__ in, __bf16* __restrict__ out, int n8) {
    int i = blockIdx.x * blockDim.x + threadIdx.x;   // chunk of 8
    if (i >= n8) return;
    const float* p = in + (size_t)i * 8;
    V16 o;
    #pragma unroll
    for (int t = 0; t < 8; t++) o.h[t] = (__bf16)p[t];
    *(float4*)(out + (size_t)i * 8) = o.f4;
}

// W [K][128] fp32 -> Wt [128][K] bf16
__global__ void k_cvt_wt(const float* __restrict__ W, __bf16* __restrict__ Wt, int K) {
    int t = blockIdx.x * blockDim.x + threadIdx.x;
    if (t >= K * HID) return;
    int k = t >> 7;
    int n = t & 127;
    Wt[(size_t)n * K + k] = (__bf16)W[t];
}

// ---------------------------------------------------------------------------
// MFMA GEMM  C[M x 128] = A[M x K] * B[K x 128],  A bf16 row-major,
// Bt = B^T bf16 [128 x K].  C bf16 out.  BM=128, BN=128, BK=32.
// Fused epilogue: als[row]=dot(Crow,a_s), ald[row]=dot(Crow,a_d)
// ---------------------------------------------------------------------------
__global__ __launch_bounds__(256) void k_gemm(const __bf16* __restrict__ A,
                                              const __bf16* __restrict__ Bt,
                                              __bf16* __restrict__ C,
                                              const float* __restrict__ a_s,
                                              const float* __restrict__ a_d,
                                              float* __restrict__ als,
                                              float* __restrict__ ald,
                                              int M, int K) {
    __shared__ __align__(16) __bf16 As[128][40];   // padded: 80 B rows
    __shared__ __align__(16) __bf16 Bs[128][40];

    int tid = threadIdx.x;
    int rowBase = blockIdx.x * 128;
    int wv = tid >> 6;        // wave 0..3
    int lane = tid & 63;
    int g = lane >> 4;        // k-slice selector (0..3)
    int c = lane & 15;        // col-in-tile / row-in-tile selector

    f32x4 acc[2][8];
    #pragma unroll
    for (int mi = 0; mi < 2; mi++)
        #pragma unroll
        for (int ni = 0; ni < 8; ni++) acc[mi][ni] = (f32x4){0.f, 0.f, 0.f, 0.f};

    for (int k0 = 0; k0 < K; k0 += 32) {
        __syncthreads();
        #pragma unroll
        for (int rep = 0; rep < 2; rep++) {
            int ch = tid + rep * 256;
            int r = ch >> 2, q = ch & 3;
            int row = rowBase + r;
            float4 v = {0.f, 0.f, 0.f, 0.f};
            if (row < M) v = *(const float4*)(A + (size_t)row * K + k0 + q * 8);
            *(float4*)&As[r][q * 8] = v;
        }
        #pragma unroll
        for (int rep = 0; rep < 2; rep++) {
            int ch = tid + rep * 256;
            int r = ch >> 2, q = ch & 3;
            float4 v = *(const float4*)(Bt + (size_t)r * K + k0 + q * 8);
            *(float4*)&Bs[r][q * 8] = v;
        }
        __syncthreads();

        bf16x8 a0 = *(const bf16x8*)&As[wv * 32 + c][g * 8];
        bf16x8 a1 = *(const bf16x8*)&As[wv * 32 + 16 + c][g * 8];
        #pragma unroll
        for (int ni = 0; ni < 8; ni++) {
            bf16x8 b = *(const bf16x8*)&Bs[ni * 16 + c][g * 8];
            acc[0][ni] = __builtin_amdgcn_mfma_f32_16x16x32_bf16(a0, b, acc[0][ni], 0, 0, 0);
            acc[1][ni] = __builtin_amdgcn_mfma_f32_16x16x32_bf16(a1, b, acc[1][ni], 0, 0, 0);
        }
    }

    float asv[8], adv[8];
    #pragma unroll
    for (int ni = 0; ni < 8; ni++) {
        asv[ni] = a_s[ni * 16 + c];
        adv[ni] = a_d[ni * 16 + c];
    }
    #pragma unroll
    for (int mi = 0; mi < 2; mi++) {
        int rb = rowBase + wv * 32 + mi * 16 + g * 4;
        #pragma unroll
        for (int i = 0; i < 4; i++) {
            int row = rb + i;
            float s = 0.f, dd = 0.f;
            #pragma unroll
            for (int ni = 0; ni < 8; ni++) {
                float v = acc[mi][ni][i];
                s = fmaf(v, asv[ni], s);
                dd = fmaf(v, adv[ni], dd);
            }
            #pragma unroll
            for (int o = 1; o <= 8; o <<= 1) {
                s += __shfl_xor(s, o);
                dd += __shfl_xor(dd, o);
            }
            if (row < M) {
                #pragma unroll
                for (int ni = 0; ni < 8; ni++)
                    C[(size_t)row * HID + ni * 16 + c] = (__bf16)acc[mi][ni][i];
                if (c == 0) {
                    als[row] = s;
                    ald[row] = dd;
                }
            }
        }
    }
}

// ---------------------------------------------------------------------------
// softmax over incoming edges: one wave per dst node. (round-3 verbatim)
// coef[j] = exp(leaky(als[src]+ald[d]) - m) / z in CSR order.
// ---------------------------------------------------------------------------
__global__ void k_softmax(const float* __restrict__ als, const float* __restrict__ ald,
                          const int* __restrict__ off, const int* __restrict__ csr,
                          float* __restrict__ coef) {
    int gt = blockIdx.x * blockDim.x + threadIdx.x;
    int d = gt >> 6;
    int lane = gt & 63;
    if (d >= NN) return;
    int e0 = off[d], e1 = off[d + 1];
    float ald_d = ald[d];

    int j0 = e0 + lane;
    float e_first = -INFINITY;
    if (j0 < e1) {
        float e = als[csr[j0]] + ald_d;
        e_first = (e > 0.0f) ? e : NEG_SLOPE * e;
    }
    float mx = e_first;
    for (int j = j0 + 64; j < e1; j += 64) {   // rare: deg > 64
        float e = als[csr[j]] + ald_d;
        e = (e > 0.0f) ? e : NEG_SLOPE * e;
        mx = fmaxf(mx, e);
    }
    #pragma unroll
    for (int o = 32; o > 0; o >>= 1) mx = fmaxf(mx, __shfl_xor(mx, o));

    float p_first = (j0 < e1) ? __expf(e_first - mx) : 0.0f;
    float z = p_first;
    for (int j = j0 + 64; j < e1; j += 64) {
        float e = als[csr[j]] + ald_d;
        e = (e > 0.0f) ? e : NEG_SLOPE * e;
        z += __expf(e - mx);
    }
    #pragma unroll
    for (int o = 32; o > 0; o >>= 1) z += __shfl_xor(z, o);
    float inv_z = 1.0f / z;   // self loop guarantees z > 0

    if (j0 < e1) coef[j0] = p_first * inv_z;
    for (int j = j0 + 64; j < e1; j += 64) {
        float e = als[csr[j]] + ald_d;
        e = (e > 0.0f) ? e : NEG_SLOPE * e;
        coef[j] = __expf(e - mx) * inv_z;
    }
}

// ---------------------------------------------------------------------------
// weighted gather: one wave per dst node, 4 edges in flight (16 lanes each),
// each lane loads 8 bf16 (16 B). (round-3 verbatim)
// y = sum_j coef[j] * h[csr[j]] + bias (+relu). out bf16 or fp32.
// ---------------------------------------------------------------------------
__global__ void k_gather(const __bf16* __restrict__ h, const int* __restrict__ off,
                         const int* __restrict__ csr, const float* __restrict__ coef,
                         const float* __restrict__ bias, void* __restrict__ yout,
                         int do_relu, int out_bf16) {
    int gt = blockIdx.x * blockDim.x + threadIdx.x;
    int d = gt >> 6;
    int lane = gt & 63;
    if (d >= NN) return;
    int grp = lane >> 4;      // edge slot 0..3
    int c = lane & 15;        // dim block (8 dims: c*8 .. c*8+7)

    int e0 = off[d], e1 = off[d + 1];
    float acc[8] = {0.f, 0.f, 0.f, 0.f, 0.f, 0.f, 0.f, 0.f};
    #pragma unroll 2
    for (int j = e0 + grp; j < e1; j += 4) {
        int s = csr[j];                  // uniform within 16-lane group
        float cf = coef[j];
        V16 v;
        v.f4 = *(const float4*)(h + (size_t)s * HID + c * 8);
        #pragma unroll
        for (int t = 0; t < 8; t++) acc[t] = fmaf(cf, (float)v.h[t], acc[t]);
    }
    // combine the 4 groups
    #pragma unroll
    for (int t = 0; t < 8; t++) {
        acc[t] += __shfl_xor(acc[t], 16);
        acc[t] += __shfl_xor(acc[t], 32);
    }

    if (grp == 0) {
        float4 b0 = *(const float4*)(bias + c * 8);
        float4 b1 = *(const float4*)(bias + c * 8 + 4);
        acc[0] += b0.x; acc[1] += b0.y; acc[2] += b0.z; acc[3] += b0.w;
        acc[4] += b1.x; acc[5] += b1.y; acc[6] += b1.z; acc[7] += b1.w;
        if (do_relu) {
            #pragma unroll
            for (int t = 0; t < 8; t++) acc[t] = fmaxf(acc[t], 0.0f);
        }
        if (out_bf16) {
            V16 o;
            #pragma unroll
            for (int t = 0; t < 8; t++) o.h[t] = (__bf16)acc[t];
            *(float4*)((__bf16*)yout + (size_t)d * HID + c * 8) = o.f4;
        } else {
            float* yf = (float*)yout + (size_t)d * HID + c * 8;
            float4 o0 = {acc[0], acc[1], acc[2], acc[3]};
            float4 o1 = {acc[4], acc[5], acc[6], acc[7]};
            *(float4*)yf = o0;
            *(float4*)(yf + 4) = o1;
        }
    }
}

// ---------------------------------------------------------------------------
// global mean pool: batch is sorted; per-block run-length accumulation
// ---------------------------------------------------------------------------
__global__ void k_pool(const float* __restrict__ emb, const int* __restrict__ batch,
                       float* __restrict__ sums, int* __restrict__ cnt) {
    int t = threadIdx.x;          // dim
    int base = blockIdx.x * 128;
    int end = base + 128;
    if (end > NN) end = NN;
    float acc = 0.0f;
    int g_cur = -1, c = 0;
    for (int n = base; n < end; ++n) {
        int g = batch[n];
        if (g != g_cur) {
            if (g_cur >= 0) {
                atomicAdd(&sums[g_cur * HID + t], acc);
                if (t == 0) atomicAdd(&cnt[g_cur], c);
            }
            acc = 0.0f;
            c = 0;
            g_cur = g;
        }
        acc += emb[(size_t)n * HID + t];
        c++;
    }
    if (g_cur >= 0) {
        atomicAdd(&sums[g_cur * HID + t], acc);
        if (t == 0) atomicAdd(&cnt[g_cur], c);
    }
}

__global__ void k_div(const float* __restrict__ sums, const int* __restrict__ cnt,
                      float* __restrict__ out) {
    int i = blockIdx.x * blockDim.x + threadIdx.x;
    if (i < NG * HID) {
        int g = i >> 7;
        float c = (float)(cnt[g] > 1 ? cnt[g] : 1);
        out[i] = sums[i] / c;
    }
}

// ---------------------------------------------------------------------------
extern "C" void kernel_launch(void* const* d_in, const int* in_sizes, int n_in,
                              void* d_out, int out_size, void* d_ws, size_t ws_size,
                              hipStream_t stream) {
    const float* x     = (const float*)d_in[0];   // [50000,256]
    const int*   ei    = (const int*)d_in[1];     // [2,800000]
    const int*   batch = (const int*)d_in[2];     // [50000]
    const float* W[3]  = {(const float*)d_in[3], (const float*)d_in[7], (const float*)d_in[11]};
    const float* AS[3] = {(const float*)d_in[4], (const float*)d_in[8], (const float*)d_in[12]};
    const float* AD[3] = {(const float*)d_in[5], (const float*)d_in[9], (const float*)d_in[13]};
    const float* BI[3] = {(const float*)d_in[6], (const float*)d_in[10], (const float*)d_in[14]};
    float* out = (float*)d_out;

    // workspace layout (~59 MB, same footprint as the proven round-4 layout)
    char* ws = (char*)d_ws;
    size_t o = 0;
    auto alloc = [&](size_t bytes) {
        void* p = ws + o;
        o = (o + bytes + 255) & ~(size_t)255;
        return p;
    };
    __bf16* xb  = (__bf16*)alloc((size_t)NN * 256 * 2);   // x in bf16 (25.6 MB)
    __bf16* hb  = (__bf16*)alloc((size_t)NN * HID * 2);   // GEMM output (12.8 MB)
    __bf16* yb  = (__bf16*)alloc((size_t)NN * HID * 2);   // layer output bf16 (12.8 MB)
    __bf16* Wt0 = (__bf16*)alloc((size_t)256 * HID * 2);
    __bf16* Wt1 = (__bf16*)alloc((size_t)HID * HID * 2);
    __bf16* Wt2 = (__bf16*)alloc((size_t)HID * HID * 2);
    float* als  = (float*)alloc(NN * 4);
    float* ald  = (float*)alloc(NN * 4);
    int* off    = (int*)alloc((NN + 1) * 4);
    int* bcnt   = (int*)alloc((NBUK + 1) * 4);
    int* bwr    = (int*)alloc((NBUK + 1) * 4);
    int* bbase  = (int*)alloc((NBUK + 1) * 4);
    int* rec    = (int*)alloc((size_t)NTE * 4);
    int* csr    = (int*)alloc((size_t)NTE * 4);
    float* sums = (float*)alloc(NG * HID * 4);
    int* cnt    = (int*)alloc(NG * 4);
    // coef aliases rec: rec is dead after k_bfill, coef written after (stream order)
    float* coef = (float*)rec;
    // final fp32 layer output aliases xb (xb dead after GEMM0)
    float* yout = (float*)xb;
    (void)ws_size; (void)in_sizes; (void)n_in; (void)out_size;

    hipMemsetAsync(bcnt, 0, 2 * (NBUK + 1) * 4 + 256, stream);  // bcnt + bwr (adjacent allocs)
    hipMemsetAsync(sums, 0, NG * HID * 4, stream);
    hipMemsetAsync(cnt, 0, NG * 4, stream);

    // ---- bucketed CSR build ----
    k_bcnt<<<NWG_E, 256, 0, stream>>>(ei, bcnt);
    k_bscan<<<1, 512, 0, stream>>>(bcnt, bbase, off);
    k_scatter<<<NWG_E, 256, 0, stream>>>(ei, bbase, bwr, rec);
    k_bfill<<<NBUK, 256, 0, stream>>>(bbase, rec, off, csr);

    // ---- conversions ----
    k_cvt_x<<<(NN * 256 / 8 + 255) / 256, 256, 0, stream>>>(x, xb, NN * 256 / 8);
    k_cvt_wt<<<(256 * HID + 255) / 256, 256, 0, stream>>>(W[0], Wt0, 256);
    k_cvt_wt<<<(HID * HID + 255) / 256, 256, 0, stream>>>(W[1], Wt1, HID);
    k_cvt_wt<<<(HID * HID + 255) / 256, 256, 0, stream>>>(W[2], Wt2, HID);

    const int gemm_grid = (NN + 127) / 128;      // 391
    const int wave_grid = (NN * 64 + 255) / 256; // 12500

    // ---- layer 0 (K=256, relu) ----
    k_gemm<<<gemm_grid, 256, 0, stream>>>(xb, Wt0, hb, AS[0], AD[0], als, ald, NN, 256);
    k_softmax<<<wave_grid, 256, 0, stream>>>(als, ald, off, csr, coef);
    k_gather<<<wave_grid, 256, 0, stream>>>(hb, off, csr, coef, BI[0], yb, 1, 1);

    // ---- layer 1 (K=128, relu) ----
    k_gemm<<<gemm_grid, 256, 0, stream>>>(yb, Wt1, hb, AS[1], AD[1], als, ald, NN, HID);
    k_softmax<<<wave_grid, 256, 0, stream>>>(als, ald, off, csr, coef);
    k_gather<<<wave_grid, 256, 0, stream>>>(hb, off, csr, coef, BI[1], yb, 1, 1);

    // ---- layer 2 (K=128, no relu) ----
    k_gemm<<<gemm_grid, 256, 0, stream>>>(yb, Wt2, hb, AS[2], AD[2], als, ald, NN, HID);
    k_softmax<<<wave_grid, 256, 0, stream>>>(als, ald, off, csr, coef);
    k_gather<<<wave_grid, 256, 0, stream>>>(hb, off, csr, coef, BI[2], yout, 0, 0);

    // ---- global mean pool ----
    k_pool<<<(NN + 127) / 128, 128, 0, stream>>>(yout, batch, sums, cnt);
    k_div<<<(NG * HID + 255) / 256, 256, 0, stream>>>(sums, cnt, out);
}

// Round 6
// 377.781 us; speedup vs baseline: 1.7929x; 1.0209x over previous
//
#include <hip/hip_runtime.h>
#include <math.h>

// Problem constants (fixed by the reference setup)
#define NN 50000          // nodes
#define NE 800000         // edges (before self loops)
#define NTE (NE + NN)     // edges incl self loops
#define NG 16             // graphs
#define HID 128           // hidden/out dim (all layers out=128)
#define NEG_SLOPE 0.2f

#define NBUK 391          // ceil(NN/128) buckets of 128 dst nodes
#define EPW 4096          // edges per workgroup in bucket count/scatter
#define NWG_E ((NTE + EPW - 1) / EPW)   // 208

typedef __attribute__((ext_vector_type(8))) __bf16 bf16x8;
typedef __attribute__((ext_vector_type(4))) float f32x4;

union V16 {
    float4 f4;
    bf16x8 b8;
    __bf16 h[8];
};

// ---------------------------------------------------------------------------
// zero init: bcnt, bwr, sums  (replaces 3 hipMemsetAsync dispatches)
// ---------------------------------------------------------------------------
__global__ void k_zero(int* __restrict__ bcnt, int* __restrict__ bwr,
                       float* __restrict__ sums) {
    int t = blockIdx.x * blockDim.x + threadIdx.x;
    if (t <= NBUK) {
        bcnt[t] = 0;
        bwr[t] = 0;
    }
    if (t < NG * HID) sums[t] = 0.0f;
}

// ---------------------------------------------------------------------------
// Bucketed CSR build.  rec[] holds src | (dst&127)<<17, grouped by bucket.
// ---------------------------------------------------------------------------
__global__ __launch_bounds__(256) void k_bcnt(const int* __restrict__ ei,
                                              int* __restrict__ bcnt) {
    __shared__ int hist[NBUK];
    int tid = threadIdx.x;
    for (int b = tid; b < NBUK; b += 256) hist[b] = 0;
    __syncthreads();
    int base = blockIdx.x * EPW;
    #pragma unroll
    for (int r = 0; r < EPW / 256; r++) {
        int idx = base + r * 256 + tid;
        if (idx < NTE) {
            int dst = (idx < NE) ? ei[NE + idx] : (idx - NE);
            atomicAdd(&hist[dst >> 7], 1);
        }
    }
    __syncthreads();
    for (int b = tid; b < NBUK; b += 256) {
        int c = hist[b];
        if (c) atomicAdd(&bcnt[b], c);
    }
}

__global__ void k_bscan(const int* __restrict__ bcnt, int* __restrict__ bbase,
                        int* __restrict__ off) {
    __shared__ int buf[512];
    int t = threadIdx.x;
    int v = (t < NBUK) ? bcnt[t] : 0;
    buf[t] = v;
    __syncthreads();
    #pragma unroll
    for (int o = 1; o < 512; o <<= 1) {
        int add = (t >= o) ? buf[t - o] : 0;
        __syncthreads();
        buf[t] += add;
        __syncthreads();
    }
    if (t < NBUK) bbase[t] = buf[t] - v;   // exclusive
    if (t == 0) {
        bbase[NBUK] = NTE;
        off[NN] = NTE;
    }
}

__global__ __launch_bounds__(256) void k_scatter(const int* __restrict__ ei,
                                                 const int* __restrict__ bbase,
                                                 int* __restrict__ bwr,
                                                 int* __restrict__ rec) {
    __shared__ int hist[NBUK];
    __shared__ int cur[NBUK];
    int tid = threadIdx.x;
    for (int b = tid; b < NBUK; b += 256) hist[b] = 0;
    __syncthreads();
    int base = blockIdx.x * EPW;
    #pragma unroll
    for (int r = 0; r < EPW / 256; r++) {
        int idx = base + r * 256 + tid;
        if (idx < NTE) {
            int dst = (idx < NE) ? ei[NE + idx] : (idx - NE);
            atomicAdd(&hist[dst >> 7], 1);
        }
    }
    __syncthreads();
    for (int b = tid; b < NBUK; b += 256) {
        int c = hist[b];
        if (c) cur[b] = bbase[b] + atomicAdd(&bwr[b], c);
    }
    __syncthreads();
    #pragma unroll
    for (int r = 0; r < EPW / 256; r++) {
        int idx = base + r * 256 + tid;
        if (idx < NTE) {
            int src, dst;
            if (idx < NE) { src = ei[idx]; dst = ei[NE + idx]; }
            else          { src = idx - NE; dst = src; }
            int pos = atomicAdd(&cur[dst >> 7], 1);
            rec[pos] = src | ((dst & 127) << 17);
        }
    }
}

// one workgroup per bucket: local 128-scan -> off[], place src into csr window
__global__ __launch_bounds__(256) void k_bfill(const int* __restrict__ bbase,
                                               const int* __restrict__ rec,
                                               int* __restrict__ off,
                                               int* __restrict__ csr) {
    __shared__ int cnt[128];
    __shared__ int scn[128];
    __shared__ int cur[128];
    int b = blockIdx.x, t = threadIdx.x;
    int base = bbase[b];
    int n = bbase[b + 1] - base;
    if (t < 128) cnt[t] = 0;
    __syncthreads();
    for (int i = t; i < n; i += 256) atomicAdd(&cnt[rec[base + i] >> 17], 1);
    __syncthreads();
    if (t < 128) scn[t] = cnt[t];
    __syncthreads();
    #pragma unroll
    for (int o = 1; o < 128; o <<= 1) {
        int add = (t >= o && t < 128) ? scn[t - o] : 0;
        __syncthreads();
        if (t < 128) scn[t] += add;
        __syncthreads();
    }
    if (t < 128) {
        int ex = scn[t] - cnt[t];
        cur[t] = ex;
        int d = b * 128 + t;
        if (d < NN) off[d] = base + ex;
    }
    __syncthreads();
    for (int i = t; i < n; i += 256) {
        int r = rec[base + i];
        int dloc = r >> 17;
        int src = r & 131071;
        int pos = atomicAdd(&cur[dloc], 1);
        csr[base + pos] = src;
    }
}

// ---------------------------------------------------------------------------
// all three weight transposes in one dispatch: W [K][128] fp32 -> Wt [128][K] bf16
// ---------------------------------------------------------------------------
__global__ void k_cvt_w(const float* __restrict__ W0, const float* __restrict__ W1,
                        const float* __restrict__ W2, __bf16* __restrict__ Wt0,
                        __bf16* __restrict__ Wt1, __bf16* __restrict__ Wt2) {
    int t = blockIdx.x * blockDim.x + threadIdx.x;
    if (t < 256 * HID) {
        int k = t >> 7, n = t & 127;
        Wt0[(size_t)n * 256 + k] = (__bf16)W0[t];
    } else if (t < 256 * HID + HID * HID) {
        int u = t - 256 * HID;
        int k = u >> 7, n = u & 127;
        Wt1[(size_t)n * HID + k] = (__bf16)W1[u];
    } else if (t < 256 * HID + 2 * HID * HID) {
        int u = t - 256 * HID - HID * HID;
        int k = u >> 7, n = u & 127;
        Wt2[(size_t)n * HID + k] = (__bf16)W2[u];
    }
}

// ---------------------------------------------------------------------------
// MFMA GEMM  C[M x 128] = A[M x K] * B[K x 128],  A row-major (fp32 or bf16,
// converted to bf16 during LDS staging), Bt = B^T bf16 [128 x K].
// C bf16 out.  BM=128, BN=128, BK=32.
// Fused epilogue: als[row]=dot(Crow,a_s), ald[row]=dot(Crow,a_d)
// ---------------------------------------------------------------------------
template <typename AT>
__global__ __launch_bounds__(256) void k_gemm(const AT* __restrict__ A,
                                              const __bf16* __restrict__ Bt,
                                              __bf16* __restrict__ C,
                                              const float* __restrict__ a_s,
                                              const float* __restrict__ a_d,
                                              float* __restrict__ als,
                                              float* __restrict__ ald,
                                              int M, int K) {
    __shared__ __align__(16) __bf16 As[128][40];   // padded: 80 B rows
    __shared__ __align__(16) __bf16 Bs[128][40];

    int tid = threadIdx.x;
    int rowBase = blockIdx.x * 128;
    int wv = tid >> 6;        // wave 0..3
    int lane = tid & 63;
    int g = lane >> 4;        // k-slice selector (0..3)
    int c = lane & 15;        // col-in-tile / row-in-tile selector

    f32x4 acc[2][8];
    #pragma unroll
    for (int mi = 0; mi < 2; mi++)
        #pragma unroll
        for (int ni = 0; ni < 8; ni++) acc[mi][ni] = (f32x4){0.f, 0.f, 0.f, 0.f};

    for (int k0 = 0; k0 < K; k0 += 32) {
        __syncthreads();
        // stage A tile (convert to bf16 if AT==float)
        #pragma unroll
        for (int rep = 0; rep < 2; rep++) {
            int ch = tid + rep * 256;
            int r = ch >> 2, q = ch & 3;
            int row = rowBase + r;
            if constexpr (sizeof(AT) == 2) {
                float4 v = {0.f, 0.f, 0.f, 0.f};
                if (row < M) v = *(const float4*)((const __bf16*)A + (size_t)row * K + k0 + q * 8);
                *(float4*)&As[r][q * 8] = v;
            } else {
                float vv[8] = {0.f, 0.f, 0.f, 0.f, 0.f, 0.f, 0.f, 0.f};
                if (row < M) {
                    const float* Ap = (const float*)A + (size_t)row * K + k0 + q * 8;
                    float4 v0 = *(const float4*)Ap;
                    float4 v1 = *(const float4*)(Ap + 4);
                    vv[0] = v0.x; vv[1] = v0.y; vv[2] = v0.z; vv[3] = v0.w;
                    vv[4] = v1.x; vv[5] = v1.y; vv[6] = v1.z; vv[7] = v1.w;
                }
                V16 o;
                #pragma unroll
                for (int t = 0; t < 8; t++) o.h[t] = (__bf16)vv[t];
                *(float4*)&As[r][q * 8] = o.f4;
            }
        }
        // stage Bt tile
        #pragma unroll
        for (int rep = 0; rep < 2; rep++) {
            int ch = tid + rep * 256;
            int r = ch >> 2, q = ch & 3;
            float4 v = *(const float4*)(Bt + (size_t)r * K + k0 + q * 8);
            *(float4*)&Bs[r][q * 8] = v;
        }
        __syncthreads();

        bf16x8 a0 = *(const bf16x8*)&As[wv * 32 + c][g * 8];
        bf16x8 a1 = *(const bf16x8*)&As[wv * 32 + 16 + c][g * 8];
        #pragma unroll
        for (int ni = 0; ni < 8; ni++) {
            bf16x8 b = *(const bf16x8*)&Bs[ni * 16 + c][g * 8];
            acc[0][ni] = __builtin_amdgcn_mfma_f32_16x16x32_bf16(a0, b, acc[0][ni], 0, 0, 0);
            acc[1][ni] = __builtin_amdgcn_mfma_f32_16x16x32_bf16(a1, b, acc[1][ni], 0, 0, 0);
        }
    }

    float asv[8], adv[8];
    #pragma unroll
    for (int ni = 0; ni < 8; ni++) {
        asv[ni] = a_s[ni * 16 + c];
        adv[ni] = a_d[ni * 16 + c];
    }
    #pragma unroll
    for (int mi = 0; mi < 2; mi++) {
        int rb = rowBase + wv * 32 + mi * 16 + g * 4;
        #pragma unroll
        for (int i = 0; i < 4; i++) {
            int row = rb + i;
            float s = 0.f, dd = 0.f;
            #pragma unroll
            for (int ni = 0; ni < 8; ni++) {
                float v = acc[mi][ni][i];
                s = fmaf(v, asv[ni], s);
                dd = fmaf(v, adv[ni], dd);
            }
            #pragma unroll
            for (int o = 1; o <= 8; o <<= 1) {
                s += __shfl_xor(s, o);
                dd += __shfl_xor(dd, o);
            }
            if (row < M) {
                #pragma unroll
                for (int ni = 0; ni < 8; ni++)
                    C[(size_t)row * HID + ni * 16 + c] = (__bf16)acc[mi][ni][i];
                if (c == 0) {
                    als[row] = s;
                    ald[row] = dd;
                }
            }
        }
    }
}

// ---------------------------------------------------------------------------
// softmax over incoming edges: one wave per dst node.
// coef[j] = exp(leaky(als[src]+ald[d]) - m) / z in CSR order.
// ---------------------------------------------------------------------------
__global__ void k_softmax(const float* __restrict__ als, const float* __restrict__ ald,
                          const int* __restrict__ off, const int* __restrict__ csr,
                          float* __restrict__ coef) {
    int gt = blockIdx.x * blockDim.x + threadIdx.x;
    int d = gt >> 6;
    int lane = gt & 63;
    if (d >= NN) return;
    int e0 = off[d], e1 = off[d + 1];
    float ald_d = ald[d];

    int j0 = e0 + lane;
    float e_first = -INFINITY;
    if (j0 < e1) {
        float e = als[csr[j0]] + ald_d;
        e_first = (e > 0.0f) ? e : NEG_SLOPE * e;
    }
    float mx = e_first;
    for (int j = j0 + 64; j < e1; j += 64) {   // rare: deg > 64
        float e = als[csr[j]] + ald_d;
        e = (e > 0.0f) ? e : NEG_SLOPE * e;
        mx = fmaxf(mx, e);
    }
    #pragma unroll
    for (int o = 32; o > 0; o >>= 1) mx = fmaxf(mx, __shfl_xor(mx, o));

    float p_first = (j0 < e1) ? __expf(e_first - mx) : 0.0f;
    float z = p_first;
    for (int j = j0 + 64; j < e1; j += 64) {
        float e = als[csr[j]] + ald_d;
        e = (e > 0.0f) ? e : NEG_SLOPE * e;
        z += __expf(e - mx);
    }
    #pragma unroll
    for (int o = 32; o > 0; o >>= 1) z += __shfl_xor(z, o);
    float inv_z = 1.0f / z;   // self loop guarantees z > 0

    if (j0 < e1) coef[j0] = p_first * inv_z;
    for (int j = j0 + 64; j < e1; j += 64) {
        float e = als[csr[j]] + ald_d;
        e = (e > 0.0f) ? e : NEG_SLOPE * e;
        coef[j] = __expf(e - mx) * inv_z;
    }
}

// ---------------------------------------------------------------------------
// weighted gather: one wave per dst node, 4 edges in flight (16 lanes each),
// each lane loads 8 bf16 (16 B).
// y = sum_j coef[j] * h[csr[j]] + bias (+relu), bf16 out.
// ---------------------------------------------------------------------------
__global__ void k_gather(const __bf16* __restrict__ h, const int* __restrict__ off,
                         const int* __restrict__ csr, const float* __restrict__ coef,
                         const float* __restrict__ bias, __bf16* __restrict__ yout,
                         int do_relu) {
    int gt = blockIdx.x * blockDim.x + threadIdx.x;
    int d = gt >> 6;
    int lane = gt & 63;
    if (d >= NN) return;
    int grp = lane >> 4;      // edge slot 0..3
    int c = lane & 15;        // dim block (8 dims: c*8 .. c*8+7)

    int e0 = off[d], e1 = off[d + 1];
    float acc[8] = {0.f, 0.f, 0.f, 0.f, 0.f, 0.f, 0.f, 0.f};
    #pragma unroll 4
    for (int j = e0 + grp; j < e1; j += 4) {
        int s = csr[j];                  // uniform within 16-lane group
        float cf = coef[j];
        V16 v;
        v.f4 = *(const float4*)(h + (size_t)s * HID + c * 8);
        #pragma unroll
        for (int t = 0; t < 8; t++) acc[t] = fmaf(cf, (float)v.h[t], acc[t]);
    }
    // combine the 4 groups
    #pragma unroll
    for (int t = 0; t < 8; t++) {
        acc[t] += __shfl_xor(acc[t], 16);
        acc[t] += __shfl_xor(acc[t], 32);
    }

    if (grp == 0) {
        float4 b0 = *(const float4*)(bias + c * 8);
        float4 b1 = *(const float4*)(bias + c * 8 + 4);
        acc[0] += b0.x; acc[1] += b0.y; acc[2] += b0.z; acc[3] += b0.w;
        acc[4] += b1.x; acc[5] += b1.y; acc[6] += b1.z; acc[7] += b1.w;
        if (do_relu) {
            #pragma unroll
            for (int t = 0; t < 8; t++) acc[t] = fmaxf(acc[t], 0.0f);
        }
        V16 o;
        #pragma unroll
        for (int t = 0; t < 8; t++) o.h[t] = (__bf16)acc[t];
        *(float4*)(yout + (size_t)d * HID + c * 8) = o.f4;
    }
}

// ---------------------------------------------------------------------------
// global mean pool: batch is sorted; per-block run-length accumulation.
// emb is bf16; accumulate fp32.
// ---------------------------------------------------------------------------
__global__ void k_pool(const __bf16* __restrict__ emb, const int* __restrict__ batch,
                       float* __restrict__ sums) {
    int t = threadIdx.x;          // dim
    int base = blockIdx.x * 128;
    int end = base + 128;
    if (end > NN) end = NN;
    float acc = 0.0f;
    int g_cur = -1;
    for (int n = base; n < end; ++n) {
        int g = batch[n];
        if (g != g_cur) {
            if (g_cur >= 0) atomicAdd(&sums[g_cur * HID + t], acc);
            acc = 0.0f;
            g_cur = g;
        }
        acc += (float)emb[(size_t)n * HID + t];
    }
    if (g_cur >= 0) atomicAdd(&sums[g_cur * HID + t], acc);
}

// counts via binary search on the sorted batch array
__global__ void k_div(const float* __restrict__ sums, const int* __restrict__ batch,
                      float* __restrict__ out) {
    int i = blockIdx.x * blockDim.x + threadIdx.x;
    if (i >= NG * HID) return;
    int g = i >> 7;
    int lo = 0, hi = NN;
    while (lo < hi) { int mid = (lo + hi) >> 1; if (batch[mid] < g) lo = mid + 1; else hi = mid; }
    int lo2 = lo, hi2 = NN;
    while (lo2 < hi2) { int mid = (lo2 + hi2) >> 1; if (batch[mid] < g + 1) lo2 = mid + 1; else hi2 = mid; }
    int c = lo2 - lo;
    out[i] = sums[i] / (float)(c > 1 ? c : 1);
}

// ---------------------------------------------------------------------------
extern "C" void kernel_launch(void* const* d_in, const int* in_sizes, int n_in,
                              void* d_out, int out_size, void* d_ws, size_t ws_size,
                              hipStream_t stream) {
    const float* x     = (const float*)d_in[0];   // [50000,256]
    const int*   ei    = (const int*)d_in[1];     // [2,800000]
    const int*   batch = (const int*)d_in[2];     // [50000]
    const float* W[3]  = {(const float*)d_in[3], (const float*)d_in[7], (const float*)d_in[11]};
    const float* AS[3] = {(const float*)d_in[4], (const float*)d_in[8], (const float*)d_in[12]};
    const float* AD[3] = {(const float*)d_in[5], (const float*)d_in[9], (const float*)d_in[13]};
    const float* BI[3] = {(const float*)d_in[6], (const float*)d_in[10], (const float*)d_in[14]};
    float* out = (float*)d_out;

    // workspace layout (~34 MB)
    char* ws = (char*)d_ws;
    size_t o = 0;
    auto alloc = [&](size_t bytes) {
        void* p = ws + o;
        o = (o + bytes + 255) & ~(size_t)255;
        return p;
    };
    __bf16* hb  = (__bf16*)alloc((size_t)NN * HID * 2);   // GEMM output (12.8 MB)
    __bf16* yb  = (__bf16*)alloc((size_t)NN * HID * 2);   // layer output bf16 (12.8 MB)
    __bf16* Wt0 = (__bf16*)alloc((size_t)256 * HID * 2);
    __bf16* Wt1 = (__bf16*)alloc((size_t)HID * HID * 2);
    __bf16* Wt2 = (__bf16*)alloc((size_t)HID * HID * 2);
    float* als  = (float*)alloc(NN * 4);
    float* ald  = (float*)alloc(NN * 4);
    int* off    = (int*)alloc((NN + 1) * 4);
    int* bcnt   = (int*)alloc((NBUK + 1) * 4);
    int* bwr    = (int*)alloc((NBUK + 1) * 4);
    int* bbase  = (int*)alloc((NBUK + 1) * 4);
    int* rec    = (int*)alloc((size_t)NTE * 4);
    int* csr    = (int*)alloc((size_t)NTE * 4);
    float* sums = (float*)alloc(NG * HID * 4);
    // coef aliases rec: rec is dead after k_bfill, coef written after (stream order)
    float* coef = (float*)rec;
    (void)ws_size; (void)in_sizes; (void)n_in; (void)out_size;

    // ---- zero init ----
    k_zero<<<(NG * HID + 255) / 256, 256, 0, stream>>>(bcnt, bwr, sums);

    // ---- bucketed CSR build ----
    k_bcnt<<<NWG_E, 256, 0, stream>>>(ei, bcnt);
    k_bscan<<<1, 512, 0, stream>>>(bcnt, bbase, off);
    k_scatter<<<NWG_E, 256, 0, stream>>>(ei, bbase, bwr, rec);
    k_bfill<<<NBUK, 256, 0, stream>>>(bbase, rec, off, csr);

    // ---- weight transposes (one dispatch) ----
    k_cvt_w<<<(256 * HID + 2 * HID * HID) / 256, 256, 0, stream>>>(
        W[0], W[1], W[2], Wt0, Wt1, Wt2);

    const int gemm_grid = (NN + 127) / 128;      // 391
    const int wave_grid = (NN * 64 + 255) / 256; // 12500

    // ---- layer 0 (K=256, A=fp32 x, relu) ----
    k_gemm<float><<<gemm_grid, 256, 0, stream>>>(x, Wt0, hb, AS[0], AD[0], als, ald, NN, 256);
    k_softmax<<<wave_grid, 256, 0, stream>>>(als, ald, off, csr, coef);
    k_gather<<<wave_grid, 256, 0, stream>>>(hb, off, csr, coef, BI[0], yb, 1);

    // ---- layer 1 (K=128, relu) ----
    k_gemm<__bf16><<<gemm_grid, 256, 0, stream>>>(yb, Wt1, hb, AS[1], AD[1], als, ald, NN, HID);
    k_softmax<<<wave_grid, 256, 0, stream>>>(als, ald, off, csr, coef);
    k_gather<<<wave_grid, 256, 0, stream>>>(hb, off, csr, coef, BI[1], yb, 1);

    // ---- layer 2 (K=128, no relu; output bf16 into yb) ----
    k_gemm<__bf16><<<gemm_grid, 256, 0, stream>>>(yb, Wt2, hb, AS[2], AD[2], als, ald, NN, HID);
    k_softmax<<<wave_grid, 256, 0, stream>>>(als, ald, off, csr, coef);
    k_gather<<<wave_grid, 256, 0, stream>>>(hb, off, csr, coef, BI[2], yb, 0);

    // ---- global mean pool ----
    k_pool<<<(NN + 127) / 128, 128, 0, stream>>>(yb, batch, sums);
    k_div<<<(NG * HID + 255) / 256, 256, 0, stream>>>(sums, batch, out);
}

// Round 7
// 345.093 us; speedup vs baseline: 1.9627x; 1.0947x over previous
//
#include <hip/hip_runtime.h>
#include <math.h>

// Problem constants (fixed by the reference setup)
#define NN 50000          // nodes
#define NE 800000         // edges (before self loops)
#define NTE (NE + NN)     // edges incl self loops
#define NG 16             // graphs
#define HID 128           // hidden/out dim (all layers out=128)
#define NEG_SLOPE 0.2f

#define NBUK 391          // ceil(NN/128) buckets of 128 dst nodes
#define EPW 4096          // edges per workgroup in bucket count/scatter
#define NWG_E ((NTE + EPW - 1) / EPW)   // 208

typedef __attribute__((ext_vector_type(8))) __bf16 bf16x8;
typedef __attribute__((ext_vector_type(4))) float f32x4;

union V16 {
    float4 f4;
    bf16x8 b8;
    __bf16 h[8];
};

// ---------------------------------------------------------------------------
// prep: zero bcnt/bwr/sums + all three weight transposes, one dispatch.
// W [K][128] fp32 -> Wt [128][K] bf16
// ---------------------------------------------------------------------------
__global__ void k_prep(int* __restrict__ bcnt, int* __restrict__ bwr,
                       float* __restrict__ sums,
                       const float* __restrict__ W0, const float* __restrict__ W1,
                       const float* __restrict__ W2, __bf16* __restrict__ Wt0,
                       __bf16* __restrict__ Wt1, __bf16* __restrict__ Wt2) {
    int t = blockIdx.x * blockDim.x + threadIdx.x;
    if (t <= NBUK) {
        bcnt[t] = 0;
        bwr[t] = 0;
    }
    if (t < NG * HID) sums[t] = 0.0f;
    if (t < 256 * HID) {
        int k = t >> 7, n = t & 127;
        Wt0[(size_t)n * 256 + k] = (__bf16)W0[t];
    } else if (t < 256 * HID + HID * HID) {
        int u = t - 256 * HID;
        int k = u >> 7, n = u & 127;
        Wt1[(size_t)n * HID + k] = (__bf16)W1[u];
    } else if (t < 256 * HID + 2 * HID * HID) {
        int u = t - 256 * HID - HID * HID;
        int k = u >> 7, n = u & 127;
        Wt2[(size_t)n * HID + k] = (__bf16)W2[u];
    }
}

// ---------------------------------------------------------------------------
// Bucketed CSR build.  rec[] holds src | (dst&127)<<17, grouped by bucket.
// ---------------------------------------------------------------------------
__global__ __launch_bounds__(256) void k_bcnt(const int* __restrict__ ei,
                                              int* __restrict__ bcnt) {
    __shared__ int hist[NBUK];
    int tid = threadIdx.x;
    for (int b = tid; b < NBUK; b += 256) hist[b] = 0;
    __syncthreads();
    int base = blockIdx.x * EPW;
    #pragma unroll
    for (int r = 0; r < EPW / 256; r++) {
        int idx = base + r * 256 + tid;
        if (idx < NTE) {
            int dst = (idx < NE) ? ei[NE + idx] : (idx - NE);
            atomicAdd(&hist[dst >> 7], 1);
        }
    }
    __syncthreads();
    for (int b = tid; b < NBUK; b += 256) {
        int c = hist[b];
        if (c) atomicAdd(&bcnt[b], c);
    }
}

__global__ void k_bscan(const int* __restrict__ bcnt, int* __restrict__ bbase,
                        int* __restrict__ off) {
    __shared__ int buf[512];
    int t = threadIdx.x;
    int v = (t < NBUK) ? bcnt[t] : 0;
    buf[t] = v;
    __syncthreads();
    #pragma unroll
    for (int o = 1; o < 512; o <<= 1) {
        int add = (t >= o) ? buf[t - o] : 0;
        __syncthreads();
        buf[t] += add;
        __syncthreads();
    }
    if (t < NBUK) bbase[t] = buf[t] - v;   // exclusive
    if (t == 0) {
        bbase[NBUK] = NTE;
        off[NN] = NTE;
    }
}

__global__ __launch_bounds__(256) void k_scatter(const int* __restrict__ ei,
                                                 const int* __restrict__ bbase,
                                                 int* __restrict__ bwr,
                                                 int* __restrict__ rec) {
    __shared__ int hist[NBUK];
    __shared__ int cur[NBUK];
    int tid = threadIdx.x;
    for (int b = tid; b < NBUK; b += 256) hist[b] = 0;
    __syncthreads();
    int base = blockIdx.x * EPW;
    #pragma unroll
    for (int r = 0; r < EPW / 256; r++) {
        int idx = base + r * 256 + tid;
        if (idx < NTE) {
            int dst = (idx < NE) ? ei[NE + idx] : (idx - NE);
            atomicAdd(&hist[dst >> 7], 1);
        }
    }
    __syncthreads();
    for (int b = tid; b < NBUK; b += 256) {
        int c = hist[b];
        if (c) cur[b] = bbase[b] + atomicAdd(&bwr[b], c);
    }
    __syncthreads();
    #pragma unroll
    for (int r = 0; r < EPW / 256; r++) {
        int idx = base + r * 256 + tid;
        if (idx < NTE) {
            int src, dst;
            if (idx < NE) { src = ei[idx]; dst = ei[NE + idx]; }
            else          { src = idx - NE; dst = src; }
            int pos = atomicAdd(&cur[dst >> 7], 1);
            rec[pos] = src | ((dst & 127) << 17);
        }
    }
}

// one workgroup per bucket: local 128-scan -> off[], place src into csr window
__global__ __launch_bounds__(256) void k_bfill(const int* __restrict__ bbase,
                                               const int* __restrict__ rec,
                                               int* __restrict__ off,
                                               int* __restrict__ csr) {
    __shared__ int cnt[128];
    __shared__ int scn[128];
    __shared__ int cur[128];
    int b = blockIdx.x, t = threadIdx.x;
    int base = bbase[b];
    int n = bbase[b + 1] - base;
    if (t < 128) cnt[t] = 0;
    __syncthreads();
    for (int i = t; i < n; i += 256) atomicAdd(&cnt[rec[base + i] >> 17], 1);
    __syncthreads();
    if (t < 128) scn[t] = cnt[t];
    __syncthreads();
    #pragma unroll
    for (int o = 1; o < 128; o <<= 1) {
        int add = (t >= o && t < 128) ? scn[t - o] : 0;
        __syncthreads();
        if (t < 128) scn[t] += add;
        __syncthreads();
    }
    if (t < 128) {
        int ex = scn[t] - cnt[t];
        cur[t] = ex;
        int d = b * 128 + t;
        if (d < NN) off[d] = base + ex;
    }
    __syncthreads();
    for (int i = t; i < n; i += 256) {
        int r = rec[base + i];
        int dloc = r >> 17;
        int src = r & 131071;
        int pos = atomicAdd(&cur[dloc], 1);
        csr[base + pos] = src;
    }
}

// ---------------------------------------------------------------------------
// MFMA GEMM  C[M x 128] = A[M x K] * B[K x 128],  A row-major (fp32 or bf16,
// converted to bf16 during LDS staging), Bt = B^T bf16 [128 x K].
// C bf16 out.  BM=128, BN=128, BK=32.
// Fused epilogue: als[row]=dot(Crow,a_s), ald[row]=dot(Crow,a_d)
// ---------------------------------------------------------------------------
template <typename AT>
__global__ __launch_bounds__(256) void k_gemm(const AT* __restrict__ A,
                                              const __bf16* __restrict__ Bt,
                                              __bf16* __restrict__ C,
                                              const float* __restrict__ a_s,
                                              const float* __restrict__ a_d,
                                              float* __restrict__ als,
                                              float* __restrict__ ald,
                                              int M, int K) {
    __shared__ __align__(16) __bf16 As[128][40];   // padded: 80 B rows
    __shared__ __align__(16) __bf16 Bs[128][40];

    int tid = threadIdx.x;
    int rowBase = blockIdx.x * 128;
    int wv = tid >> 6;        // wave 0..3
    int lane = tid & 63;
    int g = lane >> 4;        // k-slice selector (0..3)
    int c = lane & 15;        // col-in-tile / row-in-tile selector

    f32x4 acc[2][8];
    #pragma unroll
    for (int mi = 0; mi < 2; mi++)
        #pragma unroll
        for (int ni = 0; ni < 8; ni++) acc[mi][ni] = (f32x4){0.f, 0.f, 0.f, 0.f};

    for (int k0 = 0; k0 < K; k0 += 32) {
        __syncthreads();
        // stage A tile (convert to bf16 if AT==float)
        #pragma unroll
        for (int rep = 0; rep < 2; rep++) {
            int ch = tid + rep * 256;
            int r = ch >> 2, q = ch & 3;
            int row = rowBase + r;
            if constexpr (sizeof(AT) == 2) {
                float4 v = {0.f, 0.f, 0.f, 0.f};
                if (row < M) v = *(const float4*)((const __bf16*)A + (size_t)row * K + k0 + q * 8);
                *(float4*)&As[r][q * 8] = v;
            } else {
                float vv[8] = {0.f, 0.f, 0.f, 0.f, 0.f, 0.f, 0.f, 0.f};
                if (row < M) {
                    const float* Ap = (const float*)A + (size_t)row * K + k0 + q * 8;
                    float4 v0 = *(const float4*)Ap;
                    float4 v1 = *(const float4*)(Ap + 4);
                    vv[0] = v0.x; vv[1] = v0.y; vv[2] = v0.z; vv[3] = v0.w;
                    vv[4] = v1.x; vv[5] = v1.y; vv[6] = v1.z; vv[7] = v1.w;
                }
                V16 o;
                #pragma unroll
                for (int t = 0; t < 8; t++) o.h[t] = (__bf16)vv[t];
                *(float4*)&As[r][q * 8] = o.f4;
            }
        }
        // stage Bt tile
        #pragma unroll
        for (int rep = 0; rep < 2; rep++) {
            int ch = tid + rep * 256;
            int r = ch >> 2, q = ch & 3;
            float4 v = *(const float4*)(Bt + (size_t)r * K + k0 + q * 8);
            *(float4*)&Bs[r][q * 8] = v;
        }
        __syncthreads();

        bf16x8 a0 = *(const bf16x8*)&As[wv * 32 + c][g * 8];
        bf16x8 a1 = *(const bf16x8*)&As[wv * 32 + 16 + c][g * 8];
        #pragma unroll
        for (int ni = 0; ni < 8; ni++) {
            bf16x8 b = *(const bf16x8*)&Bs[ni * 16 + c][g * 8];
            acc[0][ni] = __builtin_amdgcn_mfma_f32_16x16x32_bf16(a0, b, acc[0][ni], 0, 0, 0);
            acc[1][ni] = __builtin_amdgcn_mfma_f32_16x16x32_bf16(a1, b, acc[1][ni], 0, 0, 0);
        }
    }

    float asv[8], adv[8];
    #pragma unroll
    for (int ni = 0; ni < 8; ni++) {
        asv[ni] = a_s[ni * 16 + c];
        adv[ni] = a_d[ni * 16 + c];
    }
    #pragma unroll
    for (int mi = 0; mi < 2; mi++) {
        int rb = rowBase + wv * 32 + mi * 16 + g * 4;
        #pragma unroll
        for (int i = 0; i < 4; i++) {
            int row = rb + i;
            float s = 0.f, dd = 0.f;
            #pragma unroll
            for (int ni = 0; ni < 8; ni++) {
                float v = acc[mi][ni][i];
                s = fmaf(v, asv[ni], s);
                dd = fmaf(v, adv[ni], dd);
            }
            #pragma unroll
            for (int o = 1; o <= 8; o <<= 1) {
                s += __shfl_xor(s, o);
                dd += __shfl_xor(dd, o);
            }
            if (row < M) {
                #pragma unroll
                for (int ni = 0; ni < 8; ni++)
                    C[(size_t)row * HID + ni * 16 + c] = (__bf16)acc[mi][ni][i];
                if (c == 0) {
                    als[row] = s;
                    ald[row] = dd;
                }
            }
        }
    }
}

// ---------------------------------------------------------------------------
// fused softmax + weighted gather: one wave per dst node.
// Phase 1 (== k_softmax math, verbatim): lane j handles edge e0+j;
//   cf = exp(leaky(als[src]+ald[d]) - mx) * (1/z).  Stash (src, cf) in a
//   per-wave LDS strip (same-wave write->read, no __syncthreads needed).
// Phase 2 (== k_gather loop, verbatim): 4 edges in flight (16 lanes each),
//   each lane loads 8 bf16 of h[src]; identical fma order to the split
//   kernels, so y is bitwise identical to round 6.
// deg > 64 fallback (probability ~0 at mean deg 17): strided two-pass +
//   per-edge cf recompute, arithmetic identical to the split slow path.
// ---------------------------------------------------------------------------
__global__ __launch_bounds__(256) void k_attn(const __bf16* __restrict__ h,
                                              const float* __restrict__ als,
                                              const float* __restrict__ ald,
                                              const int* __restrict__ off,
                                              const int* __restrict__ csr,
                                              const float* __restrict__ bias,
                                              __bf16* __restrict__ yout,
                                              int do_relu) {
    __shared__ int s_src[4][64];
    __shared__ float s_cf[4][64];
    int gt = blockIdx.x * blockDim.x + threadIdx.x;
    int d = gt >> 6;
    int lane = gt & 63;
    if (d >= NN) return;
    int wv = threadIdx.x >> 6;   // wave within block
    int grp = lane >> 4;         // edge slot 0..3
    int c = lane & 15;           // dim block (8 dims: c*8 .. c*8+7)

    int e0 = off[d], e1 = off[d + 1];
    int deg = e1 - e0;
    float ald_d = ald[d];
    float acc[8] = {0.f, 0.f, 0.f, 0.f, 0.f, 0.f, 0.f, 0.f};

    if (deg <= 64) {
        // ---- phase 1: softmax (k_softmax math verbatim) ----
        int s = 0;
        float e = -INFINITY;
        if (lane < deg) {
            s = csr[e0 + lane];
            float t = als[s] + ald_d;
            e = (t > 0.0f) ? t : NEG_SLOPE * t;
        }
        float mx = e;
        #pragma unroll
        for (int o = 32; o > 0; o >>= 1) mx = fmaxf(mx, __shfl_xor(mx, o));
        float p = (lane < deg) ? __expf(e - mx) : 0.0f;
        float z = p;
        #pragma unroll
        for (int o = 32; o > 0; o >>= 1) z += __shfl_xor(z, o);
        float inv_z = 1.0f / z;          // self loop guarantees z > 0
        s_src[wv][lane] = s;
        s_cf[wv][lane] = p * inv_z;      // == coef[j] of the split version

        // ---- phase 2: gather (k_gather loop verbatim, LDS-sourced) ----
        #pragma unroll 4
        for (int k = grp; k < deg; k += 4) {
            int ss = s_src[wv][k];       // uniform within 16-lane group
            float cf = s_cf[wv][k];
            V16 v;
            v.f4 = *(const float4*)(h + (size_t)ss * HID + c * 8);
            #pragma unroll
            for (int t = 0; t < 8; t++) acc[t] = fmaf(cf, (float)v.h[t], acc[t]);
        }
    } else {
        // ---- rare slow path: strided two-pass + per-edge recompute ----
        float mx = -INFINITY;
        for (int j = e0 + lane; j < e1; j += 64) {
            float t = als[csr[j]] + ald_d;
            t = (t > 0.0f) ? t : NEG_SLOPE * t;
            mx = fmaxf(mx, t);
        }
        #pragma unroll
        for (int o = 32; o > 0; o >>= 1) mx = fmaxf(mx, __shfl_xor(mx, o));
        float z = 0.0f;
        for (int j = e0 + lane; j < e1; j += 64) {
            float t = als[csr[j]] + ald_d;
            t = (t > 0.0f) ? t : NEG_SLOPE * t;
            z += __expf(t - mx);
        }
        #pragma unroll
        for (int o = 32; o > 0; o >>= 1) z += __shfl_xor(z, o);
        float inv_z = 1.0f / z;
        for (int k = grp; k < deg; k += 4) {
            int ss = csr[e0 + k];
            float t = als[ss] + ald_d;
            t = (t > 0.0f) ? t : NEG_SLOPE * t;
            float cf = __expf(t - mx) * inv_z;
            V16 v;
            v.f4 = *(const float4*)(h + (size_t)ss * HID + c * 8);
            #pragma unroll
            for (int t2 = 0; t2 < 8; t2++) acc[t2] = fmaf(cf, (float)v.h[t2], acc[t2]);
        }
    }

    // combine the 4 edge-groups
    #pragma unroll
    for (int t = 0; t < 8; t++) {
        acc[t] += __shfl_xor(acc[t], 16);
        acc[t] += __shfl_xor(acc[t], 32);
    }

    if (grp == 0) {
        float4 b0 = *(const float4*)(bias + c * 8);
        float4 b1 = *(const float4*)(bias + c * 8 + 4);
        acc[0] += b0.x; acc[1] += b0.y; acc[2] += b0.z; acc[3] += b0.w;
        acc[4] += b1.x; acc[5] += b1.y; acc[6] += b1.z; acc[7] += b1.w;
        if (do_relu) {
            #pragma unroll
            for (int t = 0; t < 8; t++) acc[t] = fmaxf(acc[t], 0.0f);
        }
        V16 o;
        #pragma unroll
        for (int t = 0; t < 8; t++) o.h[t] = (__bf16)acc[t];
        *(float4*)(yout + (size_t)d * HID + c * 8) = o.f4;
    }
}

// ---------------------------------------------------------------------------
// global mean pool: batch is sorted; per-block run-length accumulation.
// emb is bf16; accumulate fp32.
// ---------------------------------------------------------------------------
__global__ void k_pool(const __bf16* __restrict__ emb, const int* __restrict__ batch,
                       float* __restrict__ sums) {
    int t = threadIdx.x;          // dim
    int base = blockIdx.x * 128;
    int end = base + 128;
    if (end > NN) end = NN;
    float acc = 0.0f;
    int g_cur = -1;
    for (int n = base; n < end; ++n) {
        int g = batch[n];
        if (g != g_cur) {
            if (g_cur >= 0) atomicAdd(&sums[g_cur * HID + t], acc);
            acc = 0.0f;
            g_cur = g;
        }
        acc += (float)emb[(size_t)n * HID + t];
    }
    if (g_cur >= 0) atomicAdd(&sums[g_cur * HID + t], acc);
}

// counts via binary search on the sorted batch array
__global__ void k_div(const float* __restrict__ sums, const int* __restrict__ batch,
                      float* __restrict__ out) {
    int i = blockIdx.x * blockDim.x + threadIdx.x;
    if (i >= NG * HID) return;
    int g = i >> 7;
    int lo = 0, hi = NN;
    while (lo < hi) { int mid = (lo + hi) >> 1; if (batch[mid] < g) lo = mid + 1; else hi = mid; }
    int lo2 = lo, hi2 = NN;
    while (lo2 < hi2) { int mid = (lo2 + hi2) >> 1; if (batch[mid] < g + 1) lo2 = mid + 1; else hi2 = mid; }
    int c = lo2 - lo;
    out[i] = sums[i] / (float)(c > 1 ? c : 1);
}

// ---------------------------------------------------------------------------
extern "C" void kernel_launch(void* const* d_in, const int* in_sizes, int n_in,
                              void* d_out, int out_size, void* d_ws, size_t ws_size,
                              hipStream_t stream) {
    const float* x     = (const float*)d_in[0];   // [50000,256]
    const int*   ei    = (const int*)d_in[1];     // [2,800000]
    const int*   batch = (const int*)d_in[2];     // [50000]
    const float* W[3]  = {(const float*)d_in[3], (const float*)d_in[7], (const float*)d_in[11]};
    const float* AS[3] = {(const float*)d_in[4], (const float*)d_in[8], (const float*)d_in[12]};
    const float* AD[3] = {(const float*)d_in[5], (const float*)d_in[9], (const float*)d_in[13]};
    const float* BI[3] = {(const float*)d_in[6], (const float*)d_in[10], (const float*)d_in[14]};
    float* out = (float*)d_out;

    // workspace layout (~31 MB)
    char* ws = (char*)d_ws;
    size_t o = 0;
    auto alloc = [&](size_t bytes) {
        void* p = ws + o;
        o = (o + bytes + 255) & ~(size_t)255;
        return p;
    };
    __bf16* hb  = (__bf16*)alloc((size_t)NN * HID * 2);   // GEMM output (12.8 MB)
    __bf16* yb  = (__bf16*)alloc((size_t)NN * HID * 2);   // layer output bf16 (12.8 MB)
    __bf16* Wt0 = (__bf16*)alloc((size_t)256 * HID * 2);
    __bf16* Wt1 = (__bf16*)alloc((size_t)HID * HID * 2);
    __bf16* Wt2 = (__bf16*)alloc((size_t)HID * HID * 2);
    float* als  = (float*)alloc(NN * 4);
    float* ald  = (float*)alloc(NN * 4);
    int* off    = (int*)alloc((NN + 1) * 4);
    int* bcnt   = (int*)alloc((NBUK + 1) * 4);
    int* bwr    = (int*)alloc((NBUK + 1) * 4);
    int* bbase  = (int*)alloc((NBUK + 1) * 4);
    int* rec    = (int*)alloc((size_t)NTE * 4);
    int* csr    = (int*)alloc((size_t)NTE * 4);
    float* sums = (float*)alloc(NG * HID * 4);
    (void)ws_size; (void)in_sizes; (void)n_in; (void)out_size;

    // ---- prep: zero init + weight transposes (one dispatch) ----
    k_prep<<<(256 * HID + 2 * HID * HID + 255) / 256, 256, 0, stream>>>(
        bcnt, bwr, sums, W[0], W[1], W[2], Wt0, Wt1, Wt2);

    // ---- bucketed CSR build ----
    k_bcnt<<<NWG_E, 256, 0, stream>>>(ei, bcnt);
    k_bscan<<<1, 512, 0, stream>>>(bcnt, bbase, off);
    k_scatter<<<NWG_E, 256, 0, stream>>>(ei, bbase, bwr, rec);
    k_bfill<<<NBUK, 256, 0, stream>>>(bbase, rec, off, csr);

    const int gemm_grid = (NN + 127) / 128;      // 391
    const int wave_grid = (NN * 64 + 255) / 256; // 12500

    // ---- layer 0 (K=256, A=fp32 x, relu) ----
    k_gemm<float><<<gemm_grid, 256, 0, stream>>>(x, Wt0, hb, AS[0], AD[0], als, ald, NN, 256);
    k_attn<<<wave_grid, 256, 0, stream>>>(hb, als, ald, off, csr, BI[0], yb, 1);

    // ---- layer 1 (K=128, relu) ----
    k_gemm<__bf16><<<gemm_grid, 256, 0, stream>>>(yb, Wt1, hb, AS[1], AD[1], als, ald, NN, HID);
    k_attn<<<wave_grid, 256, 0, stream>>>(hb, als, ald, off, csr, BI[1], yb, 1);

    // ---- layer 2 (K=128, no relu) ----
    k_gemm<__bf16><<<gemm_grid, 256, 0, stream>>>(yb, Wt2, hb, AS[2], AD[2], als, ald, NN, HID);
    k_attn<<<wave_grid, 256, 0, stream>>>(hb, als, ald, off, csr, BI[2], yb, 0);

    // ---- global mean pool ----
    k_pool<<<(NN + 127) / 128, 128, 0, stream>>>(yb, batch, sums);
    k_div<<<(NG * HID + 255) / 256, 256, 0, stream>>>(sums, batch, out);
}